// Round 1
// 263.274 us; speedup vs baseline: 1.0582x; 1.0582x over previous
//
#include <hip/hip_runtime.h>
#include <hip/hip_bf16.h>

#define D_MODEL 1024
#define N_SEQ   2048
#define N_B     2
#define M_ROWS  (N_B * N_SEQ)   // 4096

typedef __attribute__((ext_vector_type(8))) short bf16x8;
typedef __attribute__((ext_vector_type(4))) float f32x4;

typedef const __attribute__((address_space(1))) unsigned int gu32_t;
typedef __attribute__((address_space(3))) unsigned int lu32_t;

__device__ __forceinline__ void gload16(const void* g, void* l) {
  // async global->LDS, 16B per lane; LDS dest = wave-uniform base + lane*16
  __builtin_amdgcn_global_load_lds((gu32_t*)g, (lu32_t*)l, 16, 0, 0);
}

__device__ inline unsigned short f2bf(float f) {
  union { float f; unsigned int u; } v; v.f = f;
  unsigned int r = (v.u + 0x7FFFu + ((v.u >> 16) & 1u)) >> 16;
  return (unsigned short)r;
}

// packed f32x2 -> bf16x2 (RNE); no builtin on gfx950, per learn_hip m240
__device__ __forceinline__ unsigned int cvt_pk_bf16(float a, float b) {
  unsigned int r;
  asm("v_cvt_pk_bf16_f32 %0, %1, %2" : "=v"(r) : "v"(a), "v"(b));
  return r;
}

__device__ __forceinline__ float exp2fast(float x) {
#if __has_builtin(__builtin_amdgcn_exp2f)
  return __builtin_amdgcn_exp2f(x);
#else
  return __expf(x * 0.69314718056f);
#endif
}

// Bank-conflict swizzle for 64-col (128B-row) LDS tiles:
// logical 16B-chunk k of row r lives at physical chunk k ^ (r & 7).
__device__ __forceinline__ int lds_off(int row, int col /*ushort idx*/) {
  return row * 64 + (((col >> 3) ^ (row & 7)) << 3) + (col & 7);
}

// Stage a ROWS x 64-ushort tile global->LDS with the swizzle applied on the
// global-source side (LDS destination must stay linear for global_load_lds).
template<int ROWS>
__device__ __forceinline__ void stage_tile(const unsigned short* gbase, size_t gstride,
                                           unsigned short* lds, int tid) {
  const int wave = tid >> 6;
#pragma unroll
  for (int rnd = 0; rnd < ROWS / 32; ++rnd) {
    int c = rnd * 256 + tid;
    int row = c >> 3, pc = c & 7;
    int gcol = ((pc ^ (row & 7)) << 3);
    gload16(gbase + (size_t)row * gstride + gcol,
            lds + (size_t)(rnd * 256 + wave * 64) * 8);
  }
}

constexpr size_t XEL = (size_t)M_ROWS * D_MODEL;     // 4194304
constexpr size_t WEL = (size_t)D_MODEL * D_MODEL;    // 1048576

// ---------------------------------------------------------------------------
// fp32 -> bf16 convert for [x (4M) | Wq | Wk | Wv | Wo (1M each)] -> ws
// ---------------------------------------------------------------------------
__launch_bounds__(256)
__global__ void cvt_kernel(const float* __restrict__ x,
                           const float* __restrict__ wq, const float* __restrict__ wk,
                           const float* __restrict__ wv, const float* __restrict__ wo,
                           unsigned short* __restrict__ dst) {
  size_t i = ((size_t)blockIdx.x * 256 + threadIdx.x) * 8;
  if (i >= XEL + 4 * WEL) return;
  const float* s; size_t off = i;
  if (off < XEL)                { s = x; }
  else if (off < XEL + WEL)     { s = wq; off -= XEL; }
  else if (off < XEL + 2*WEL)   { s = wk; off -= XEL + WEL; }
  else if (off < XEL + 3*WEL)   { s = wv; off -= XEL + 2*WEL; }
  else                          { s = wo; off -= XEL + 3*WEL; }
  float4 f0 = *(const float4*)(s + off);
  float4 f1 = *(const float4*)(s + off + 4);
  unsigned short t[8] = { f2bf(f0.x), f2bf(f0.y), f2bf(f0.z), f2bf(f0.w),
                          f2bf(f1.x), f2bf(f1.y), f2bf(f1.z), f2bf(f1.w) };
  *(uint4*)(dst + i) = *(const uint4*)t;
}

// ---------------------------------------------------------------------------
// m97-style 128x128 bf16 mainloop, swizzled LDS: C = A * Bw^T
// ---------------------------------------------------------------------------
__device__ __forceinline__ void mainloop128(const unsigned short* __restrict__ A,
                                            const unsigned short* __restrict__ Bw,
                                            int m0, int e0,
                                            unsigned short* As, unsigned short* Bs,
                                            f32x4 (&acc)[4][4]) {
  const int tid  = threadIdx.x;
  const int wave = tid >> 6, lane = tid & 63;
  const int l16 = lane & 15, quad = lane >> 4;
  const int wr = wave >> 1, wc = wave & 1;

  for (int kt = 0; kt < D_MODEL / 64; ++kt) {
    const int k0 = kt * 64;
    stage_tile<128>(A + (size_t)m0 * D_MODEL + k0, D_MODEL, As, tid);
    stage_tile<128>(Bw + (size_t)e0 * D_MODEL + k0, D_MODEL, Bs, tid);
    __syncthreads();
#pragma unroll
    for (int ks = 0; ks < 2; ++ks) {
      bf16x8 af[4], bfr[4];
#pragma unroll
      for (int mi = 0; mi < 4; ++mi)
        af[mi] = *(const bf16x8*)(As + lds_off(wr * 64 + mi * 16 + l16, ks * 32 + quad * 8));
#pragma unroll
      for (int ci = 0; ci < 4; ++ci)
        bfr[ci] = *(const bf16x8*)(Bs + lds_off(wc * 64 + ci * 16 + l16, ks * 32 + quad * 8));
#pragma unroll
      for (int mi = 0; mi < 4; ++mi)
#pragma unroll
        for (int ci = 0; ci < 4; ++ci)
          acc[mi][ci] = __builtin_amdgcn_mfma_f32_16x16x32_bf16(af[mi], bfr[ci], acc[mi][ci], 0, 0, 0);
    }
    __syncthreads();
  }
}

// ---------------------------------------------------------------------------
// Fused Q/K/V projection. grid (32, 24): by -> {mat = by>>3, e0 = (by&7)*128}.
// mat 0 (q): LN epilogue with 0.125*log2e softmax/exp2 scale folded in.
// mat 1 (k): LN epilogue.
// mat 2 (v): V stored TRANSPOSED per (b,h), keys sigma-permuted within each
//            32-block so attn's in-register P^T fragment lines up with V.
// ---------------------------------------------------------------------------
__launch_bounds__(256)
__global__ void qkv_gemm(const unsigned short* __restrict__ xb,
                         const unsigned short* __restrict__ wb,   // wq|wk|wv bf16
                         const float* __restrict__ bq, const float* __restrict__ bk,
                         const float* __restrict__ bv,
                         const float* __restrict__ qg, const float* __restrict__ qbeta,
                         const float* __restrict__ kg, const float* __restrict__ kbeta,
                         unsigned short* __restrict__ qkout,      // qn | kn
                         unsigned short* __restrict__ vt) {
  __shared__ unsigned short As[128 * 64];
  __shared__ unsigned short Bs[128 * 64];
  const int m0  = blockIdx.x * 128;
  const int by  = blockIdx.y;
  const int mat = by >> 3;
  const int e0  = (by & 7) * 128;
  const unsigned short* Bw = wb + (size_t)mat * WEL;

  f32x4 acc[4][4];
#pragma unroll
  for (int mi = 0; mi < 4; ++mi)
#pragma unroll
    for (int ci = 0; ci < 4; ++ci) acc[mi][ci] = f32x4{0.f, 0.f, 0.f, 0.f};

  mainloop128(xb, Bw, m0, e0, As, Bs, acc);

  const int lane = threadIdx.x & 63, wave = threadIdx.x >> 6;
  const int l16 = lane & 15, quad = lane >> 4;
  const int wr = wave >> 1, wc = wave & 1;
  const int colbase = e0 + wc * 64;          // multiple of 64 -> one head per wave

  const float* bias = (mat == 0) ? bq : ((mat == 1) ? bk : bv);
  float bcol[4];
#pragma unroll
  for (int ci = 0; ci < 4; ++ci) bcol[ci] = bias[colbase + ci * 16 + l16];
#pragma unroll
  for (int mi = 0; mi < 4; ++mi)
#pragma unroll
    for (int ci = 0; ci < 4; ++ci)
#pragma unroll
      for (int r = 0; r < 4; ++r) acc[mi][ci][r] += bcol[ci];

  if (mat < 2) {
    const float* gamma = (mat == 0) ? qg : kg;
    const float* beta  = (mat == 0) ? qbeta : kbeta;
    // fold softmax scale AND log2(e) (attn uses exp2) into q
    const float sc = (mat == 0) ? 0.18033688011112042f : 1.0f;  // 0.125*log2e
    float g4[4], bt4[4];
#pragma unroll
    for (int ci = 0; ci < 4; ++ci) {
      g4[ci] = gamma[ci * 16 + l16] * sc;
      bt4[ci] = beta[ci * 16 + l16] * sc;
    }
#pragma unroll
    for (int mi = 0; mi < 4; ++mi)
#pragma unroll
      for (int r = 0; r < 4; ++r) {
        float s = acc[mi][0][r] + acc[mi][1][r] + acc[mi][2][r] + acc[mi][3][r];
        s += __shfl_xor(s, 1); s += __shfl_xor(s, 2);
        s += __shfl_xor(s, 4); s += __shfl_xor(s, 8);
        float mean = s * (1.f / 64.f);
        float d0 = acc[mi][0][r] - mean, d1 = acc[mi][1][r] - mean;
        float d2 = acc[mi][2][r] - mean, d3 = acc[mi][3][r] - mean;
        float q = d0 * d0 + d1 * d1 + d2 * d2 + d3 * d3;
        q += __shfl_xor(q, 1); q += __shfl_xor(q, 2);
        q += __shfl_xor(q, 4); q += __shfl_xor(q, 8);
        float rs = rsqrtf(q * (1.f / 64.f) + 1e-6f);
        acc[mi][0][r] = d0 * rs * g4[0] + bt4[0];
        acc[mi][1][r] = d1 * rs * g4[1] + bt4[1];
        acc[mi][2][r] = d2 * rs * g4[2] + bt4[2];
        acc[mi][3][r] = d3 * rs * g4[3] + bt4[3];
      }
    unsigned short* out = qkout + (size_t)mat * XEL;
#pragma unroll
    for (int mi = 0; mi < 4; ++mi)
#pragma unroll
      for (int ci = 0; ci < 4; ++ci) {
        int col = colbase + ci * 16 + l16;
#pragma unroll
        for (int r = 0; r < 4; ++r) {
          int row = m0 + wr * 64 + mi * 16 + quad * 4 + r;
          out[(size_t)row * D_MODEL + col] = f2bf(acc[mi][ci][r]);
        }
      }
  } else {
    // V transpose via wave-private LDS scratch (col-swizzled), then each lane
    // stores one full d-row (128B) as 8x dwordx4 -> coalesced.
    // Token index within 64 is sigma-permuted: logical t = 16*half+4*q+r
    // stored at phys = 8*q + 4*half + r (within its 32-block), matching the
    // attention kernel's in-register P^T bf16x8 fragment order.
    unsigned short* scr = ((wave < 2) ? As : Bs) + (size_t)(wave & 1) * 4096;
#pragma unroll
    for (int ci = 0; ci < 4; ++ci) {
      int dl = ci * 16 + l16;
      int sw = (dl & 3) * 16;
#pragma unroll
      for (int mi = 0; mi < 4; ++mi)
#pragma unroll
        for (int r = 0; r < 4; ++r) {
          // logical token t = mi*16 + quad*4 + r  (half = mi&1, block = mi>>1)
          int np = ((mi >> 1) << 5) + (quad << 3) + ((mi & 1) << 2) + r;
          scr[dl * 64 + (np ^ sw)] = f2bf(acc[mi][ci][r]);
        }
    }
    __builtin_amdgcn_wave_barrier();
    int row0 = m0 + wr * 64;                 // token base of this wave's tile
    int b = row0 >> 11, nb = row0 & 2047;
    int h = colbase >> 6;
    int dl = lane;                           // this lane's d within the head
    unsigned short* gdst = vt + ((size_t)((b * 16 + h) * 64 + dl) * N_SEQ + nb);
    const unsigned short* srow = scr + dl * 64;
    int sw = (dl & 3) * 16;
#pragma unroll
    for (int j = 0; j < 8; ++j) {
      uint4 vv = *(const uint4*)(srow + ((j * 8) ^ sw));
      *(uint4*)(gdst + j * 8) = vv;
    }
  }
}

// ---------------------------------------------------------------------------
// Output projection: fp32 out = ao * Wo^T + bo. grid (32, 8).
// ---------------------------------------------------------------------------
__launch_bounds__(256)
__global__ void out_gemm(const unsigned short* __restrict__ ao,
                         const unsigned short* __restrict__ wob,
                         const float* __restrict__ bo,
                         float* __restrict__ out) {
  __shared__ unsigned short As[128 * 64];
  __shared__ unsigned short Bs[128 * 64];
  const int m0 = blockIdx.x * 128;
  const int e0 = blockIdx.y * 128;

  f32x4 acc[4][4];
#pragma unroll
  for (int mi = 0; mi < 4; ++mi)
#pragma unroll
    for (int ci = 0; ci < 4; ++ci) acc[mi][ci] = f32x4{0.f, 0.f, 0.f, 0.f};

  mainloop128(ao, wob, m0, e0, As, Bs, acc);

  const int lane = threadIdx.x & 63, wave = threadIdx.x >> 6;
  const int l16 = lane & 15, quad = lane >> 4;
  const int wr = wave >> 1, wc = wave & 1;
  float bcol[4];
#pragma unroll
  for (int ci = 0; ci < 4; ++ci) bcol[ci] = bo[e0 + wc * 64 + ci * 16 + l16];
#pragma unroll
  for (int mi = 0; mi < 4; ++mi)
#pragma unroll
    for (int ci = 0; ci < 4; ++ci) {
      int col = e0 + wc * 64 + ci * 16 + l16;
#pragma unroll
      for (int r = 0; r < 4; ++r) {
        int row = m0 + wr * 64 + mi * 16 + quad * 4 + r;
        out[(size_t)row * D_MODEL + col] = acc[mi][ci][r] + bcol[ci];
      }
    }
}

// ---------------------------------------------------------------------------
// Flash attention, swapped-operand QK^T: S^T = mfma(K,Q) puts 4 CONSECUTIVE
// keys per lane per 16-tile, so (a) bias loads vectorize to float4 (and are
// double-buffered across kt -> latency hidden under a full tile of compute),
// (b) P^T is packed to bf16 fragments IN-REGISTER via v_cvt_pk_bf16_f32 (no
// LDS round-trip, no wave barriers), (c) PV runs as O^T = mfma(V^T, P^T)
// against the sigma-permuted Vt layout with the same b128 V reads as before,
// (d) l-normalization is lane-local and stores are 8B-vectorized.
// No running max (LN'd q,k + |bias| bound -> exp2 safe). Grid 512 = 2/CU.
// ---------------------------------------------------------------------------
__launch_bounds__(256)
__global__ void attn_kernel(const unsigned short* __restrict__ Q,
                            const unsigned short* __restrict__ Kn,
                            const unsigned short* __restrict__ Vt,
                            const float* __restrict__ bias,
                            unsigned short* __restrict__ Out) {
  __shared__ unsigned short Qs[128 * 64];
  __shared__ unsigned short Ks[2][64 * 64];
  __shared__ unsigned short Vts[2][64 * 64];
  const int tid  = threadIdx.x;
  const int wave = tid >> 6, lane = tid & 63;
  const int quad = lane >> 4, l16 = lane & 15;
  const int bidx = blockIdx.x;
  const int qt = bidx & 15;                  // 16 q-tiles of 128
  const int h  = (bidx >> 4) & 15;
  const int b  = bidx >> 8;
  const int q0 = qt * 128;
  const size_t base  = (size_t)b * N_SEQ * D_MODEL + (size_t)h * 64;
  const unsigned short* vtb = Vt + (size_t)(b * 16 + h) * 64 * N_SEQ;

  // ---- stage Q (128 rows) + K/V tile 0 ----
  stage_tile<128>(Q + base + (size_t)q0 * D_MODEL, D_MODEL, Qs, tid);
  stage_tile<64>(Kn + base, D_MODEL, Ks[0], tid);
  stage_tile<64>(vtb, N_SEQ, Vts[0], tid);

  // bias row pointers for this lane's q-rows (S^T layout: q = l16)
  const float* brow[2];
#pragma unroll
  for (int mi = 0; mi < 2; ++mi)
    brow[mi] = bias + ((size_t)b * N_SEQ + q0 + wave * 32 + mi * 16 + l16) * N_SEQ;

  // double-buffered bias tile in regs: bcur = tile kt, bnxt = tile kt+1
  f32x4 bcur[2][4], bnxt[2][4];
#pragma unroll
  for (int mi = 0; mi < 2; ++mi)
#pragma unroll
    for (int c = 0; c < 4; ++c)
      bcur[mi][c] = *(const f32x4*)(brow[mi] + c * 16 + quad * 4);

  __syncthreads();
  bf16x8 aq[2][2];                           // [mi][ks]
#pragma unroll
  for (int mi = 0; mi < 2; ++mi)
#pragma unroll
    for (int ks = 0; ks < 2; ++ks)
      aq[mi][ks] = *(const bf16x8*)(Qs + lds_off(wave * 32 + mi * 16 + l16, ks * 32 + quad * 8));

  f32x4 o[2][4];                             // O^T: row d = cd*16+quad*4+r, col q = l16
#pragma unroll
  for (int mi = 0; mi < 2; ++mi)
#pragma unroll
    for (int cd = 0; cd < 4; ++cd) o[mi][cd] = f32x4{0.f, 0.f, 0.f, 0.f};
  float lsum[2] = {0.f, 0.f};
  constexpr float LOG2E = 1.44269504088896340736f;

  constexpr int NT = N_SEQ / 64;
  for (int kt = 0; kt < NT; ++kt) {
    const int cur = kt & 1;
    if (kt + 1 < NT) {                       // prefetch overlaps this tile
      stage_tile<64>(Kn + base + (size_t)(kt + 1) * 64 * D_MODEL, D_MODEL, Ks[cur ^ 1], tid);
      stage_tile<64>(vtb + (kt + 1) * 64, N_SEQ, Vts[cur ^ 1], tid);
#pragma unroll
      for (int mi = 0; mi < 2; ++mi)
#pragma unroll
        for (int c = 0; c < 4; ++c)
          bnxt[mi][c] = *(const f32x4*)(brow[mi] + (kt + 1) * 64 + c * 16 + quad * 4);
    }

    // S^T = K Q^T (q pre-scaled by 0.125*log2e in its LN)
    f32x4 sfT[2][4];                         // [mi][c]: key = c*16+quad*4+r, q = l16
#pragma unroll
    for (int c = 0; c < 4; ++c) {
      bf16x8 k0 = *(const bf16x8*)(Ks[cur] + lds_off(c * 16 + l16, quad * 8));
      bf16x8 k1 = *(const bf16x8*)(Ks[cur] + lds_off(c * 16 + l16, 32 + quad * 8));
#pragma unroll
      for (int mi = 0; mi < 2; ++mi) {
        f32x4 z = f32x4{0.f, 0.f, 0.f, 0.f};
        z = __builtin_amdgcn_mfma_f32_16x16x32_bf16(k0, aq[mi][0], z, 0, 0, 0);
        sfT[mi][c] = __builtin_amdgcn_mfma_f32_16x16x32_bf16(k1, aq[mi][1], z, 0, 0, 0);
      }
    }

    // p = 2^(sT + bias*log2e); accumulate l per lane; pack P^T to bf16 frags.
    // paf[mi][ks] element e on lane(quad,l16) holds key 32*ks+16*(e>>2)+4*quad+(e&3)
    // -- exactly the sigma-permuted V layout's k-slot order.
    union PafU { unsigned int w[4]; bf16x8 v; };
    PafU paf[2][2];
#pragma unroll
    for (int mi = 0; mi < 2; ++mi)
#pragma unroll
      for (int c = 0; c < 4; ++c) {
        float p0 = exp2fast(fmaf(bcur[mi][c][0], LOG2E, sfT[mi][c][0]));
        float p1 = exp2fast(fmaf(bcur[mi][c][1], LOG2E, sfT[mi][c][1]));
        float p2 = exp2fast(fmaf(bcur[mi][c][2], LOG2E, sfT[mi][c][2]));
        float p3 = exp2fast(fmaf(bcur[mi][c][3], LOG2E, sfT[mi][c][3]));
        lsum[mi] += (p0 + p1) + (p2 + p3);
        paf[mi][c >> 1].w[(c & 1) * 2]     = cvt_pk_bf16(p0, p1);
        paf[mi][c >> 1].w[(c & 1) * 2 + 1] = cvt_pk_bf16(p2, p3);
      }

    // O^T += V^T P^T  (V frags reused across both mi)
#pragma unroll
    for (int ks = 0; ks < 2; ++ks) {
      bf16x8 bv[4];
#pragma unroll
      for (int cd = 0; cd < 4; ++cd)
        bv[cd] = *(const bf16x8*)(Vts[cur] + lds_off(cd * 16 + l16, ks * 32 + quad * 8));
#pragma unroll
      for (int mi = 0; mi < 2; ++mi)
#pragma unroll
        for (int cd = 0; cd < 4; ++cd)
          o[mi][cd] = __builtin_amdgcn_mfma_f32_16x16x32_bf16(bv[cd], paf[mi][ks].v, o[mi][cd], 0, 0, 0);
    }
    __syncthreads();   // all waves done with buf cur; prefetch cur^1 drained
#pragma unroll
    for (int mi = 0; mi < 2; ++mi)
#pragma unroll
      for (int c = 0; c < 4; ++c) bcur[mi][c] = bnxt[mi][c];
  }

  // normalize: lsum and O^T columns are both indexed by q = l16 -> lane-local.
#pragma unroll
  for (int mi = 0; mi < 2; ++mi) {
    float l = lsum[mi];
    l += __shfl_xor(l, 16);
    l += __shfl_xor(l, 32);
    float inv = 1.0f / l;
    size_t row = (size_t)b * N_SEQ + q0 + wave * 32 + mi * 16 + l16;
#pragma unroll
    for (int cd = 0; cd < 4; ++cd) {
      uint2 vv;
      vv.x = cvt_pk_bf16(o[mi][cd][0] * inv, o[mi][cd][1] * inv);
      vv.y = cvt_pk_bf16(o[mi][cd][2] * inv, o[mi][cd][3] * inv);
      *(uint2*)(Out + row * D_MODEL + h * 64 + cd * 16 + quad * 4) = vv;
    }
  }
}

extern "C" void kernel_launch(void* const* d_in, const int* in_sizes, int n_in,
                              void* d_out, int out_size, void* d_ws, size_t ws_size,
                              hipStream_t stream) {
  const float* x    = (const float*)d_in[0];
  const float* bias = (const float*)d_in[1];
  const float* Wq = (const float*)d_in[2];  const float* bq = (const float*)d_in[3];
  const float* Wk = (const float*)d_in[4];  const float* bk = (const float*)d_in[5];
  const float* Wv = (const float*)d_in[6];  const float* bv = (const float*)d_in[7];
  const float* Wo = (const float*)d_in[8];  const float* bo = (const float*)d_in[9];
  const float* qg = (const float*)d_in[10]; const float* qb = (const float*)d_in[11];
  const float* kg = (const float*)d_in[12]; const float* kb = (const float*)d_in[13];
  float* out = (float*)d_out;

  unsigned short* wsb = (unsigned short*)d_ws;
  unsigned short* xb  = wsb;                 // 4M (reused as ao after qkv_gemm)
  unsigned short* wqb = wsb + XEL;           // 4 x 1M weights
  unsigned short* wob = wsb + XEL + 3 * WEL;
  unsigned short* qn  = wsb + XEL + 4 * WEL; // 4M
  unsigned short* kn  = qn + XEL;            // 4M
  unsigned short* vt  = qn + 2 * XEL;        // 4M, transposed + key-permuted
  unsigned short* ao  = xb;                  // alias: xb dead after qkv_gemm

  dim3 blk(256, 1, 1);

  cvt_kernel<<<dim3((unsigned)((XEL + 4 * WEL) / (256 * 8)), 1, 1), blk, 0, stream>>>(
      x, Wq, Wk, Wv, Wo, wsb);

  qkv_gemm<<<dim3(M_ROWS / 128, 24, 1), blk, 0, stream>>>(
      xb, wqb, bq, bk, bv, qg, qb, kg, kb, qn, vt);

  attn_kernel<<<dim3(N_B * 16 * (N_SEQ / 128), 1, 1), blk, 0, stream>>>(qn, kn, vt, bias, ao);

  out_gemm<<<dim3(M_ROWS / 128, D_MODEL / 128, 1), blk, 0, stream>>>(ao, wob, bo, out);
}

// Round 3
// 259.075 us; speedup vs baseline: 1.0754x; 1.0162x over previous
//
#include <hip/hip_runtime.h>
#include <hip/hip_bf16.h>

#define D_MODEL 1024
#define N_SEQ   2048
#define N_B     2
#define M_ROWS  (N_B * N_SEQ)   // 4096

typedef __attribute__((ext_vector_type(8))) short bf16x8;
typedef __attribute__((ext_vector_type(4))) float f32x4;

typedef const __attribute__((address_space(1))) unsigned int gu32_t;
typedef __attribute__((address_space(3))) unsigned int lu32_t;

__device__ __forceinline__ void gload16(const void* g, void* l) {
  // async global->LDS, 16B per lane; LDS dest = wave-uniform base + lane*16
  __builtin_amdgcn_global_load_lds((gu32_t*)g, (lu32_t*)l, 16, 0, 0);
}

__device__ inline unsigned short f2bf(float f) {
  union { float f; unsigned int u; } v; v.f = f;
  unsigned int r = (v.u + 0x7FFFu + ((v.u >> 16) & 1u)) >> 16;
  return (unsigned short)r;
}

// packed f32x2 -> bf16x2 (RNE); no builtin on gfx950, per learn_hip m240
__device__ __forceinline__ unsigned int cvt_pk_bf16(float a, float b) {
  unsigned int r;
  asm("v_cvt_pk_bf16_f32 %0, %1, %2" : "=v"(r) : "v"(a), "v"(b));
  return r;
}

__device__ __forceinline__ float exp2fast(float x) {
#if __has_builtin(__builtin_amdgcn_exp2f)
  return __builtin_amdgcn_exp2f(x);
#else
  return __expf(x * 0.69314718056f);
#endif
}

// Bank-conflict swizzle for 64-col (128B-row) LDS tiles:
// logical 16B-chunk k of row r lives at physical chunk k ^ (r & 7).
__device__ __forceinline__ int lds_off(int row, int col /*ushort idx*/) {
  return row * 64 + (((col >> 3) ^ (row & 7)) << 3) + (col & 7);
}

// Stage a ROWS x 64-ushort tile global->LDS with the swizzle applied on the
// global-source side (LDS destination must stay linear for global_load_lds).
template<int ROWS, int NTHR = 256>
__device__ __forceinline__ void stage_tile(const unsigned short* gbase, size_t gstride,
                                           unsigned short* lds, int tid) {
  const int wave = tid >> 6;
#pragma unroll
  for (int rnd = 0; rnd < ROWS * 8 / NTHR; ++rnd) {
    int c = rnd * NTHR + tid;
    int row = c >> 3, pc = c & 7;
    int gcol = ((pc ^ (row & 7)) << 3);
    gload16(gbase + (size_t)row * gstride + gcol,
            lds + (size_t)(rnd * NTHR + wave * 64) * 8);
  }
}

constexpr size_t XEL = (size_t)M_ROWS * D_MODEL;     // 4194304
constexpr size_t WEL = (size_t)D_MODEL * D_MODEL;    // 1048576

// ---------------------------------------------------------------------------
// fp32 -> bf16 convert for [x (4M) | Wq | Wk | Wv | Wo (1M each)] -> ws
// ---------------------------------------------------------------------------
__launch_bounds__(256)
__global__ void cvt_kernel(const float* __restrict__ x,
                           const float* __restrict__ wq, const float* __restrict__ wk,
                           const float* __restrict__ wv, const float* __restrict__ wo,
                           unsigned short* __restrict__ dst) {
  size_t i = ((size_t)blockIdx.x * 256 + threadIdx.x) * 8;
  if (i >= XEL + 4 * WEL) return;
  const float* s; size_t off = i;
  if (off < XEL)                { s = x; }
  else if (off < XEL + WEL)     { s = wq; off -= XEL; }
  else if (off < XEL + 2*WEL)   { s = wk; off -= XEL + WEL; }
  else if (off < XEL + 3*WEL)   { s = wv; off -= XEL + 2*WEL; }
  else                          { s = wo; off -= XEL + 3*WEL; }
  float4 f0 = *(const float4*)(s + off);
  float4 f1 = *(const float4*)(s + off + 4);
  unsigned short t[8] = { f2bf(f0.x), f2bf(f0.y), f2bf(f0.z), f2bf(f0.w),
                          f2bf(f1.x), f2bf(f1.y), f2bf(f1.z), f2bf(f1.w) };
  *(uint4*)(dst + i) = *(const uint4*)t;
}

// ---------------------------------------------------------------------------
// m97-style 128x128 bf16 mainloop, swizzled LDS: C = A * Bw^T
// ---------------------------------------------------------------------------
__device__ __forceinline__ void mainloop128(const unsigned short* __restrict__ A,
                                            const unsigned short* __restrict__ Bw,
                                            int m0, int e0,
                                            unsigned short* As, unsigned short* Bs,
                                            f32x4 (&acc)[4][4]) {
  const int tid  = threadIdx.x;
  const int wave = tid >> 6, lane = tid & 63;
  const int l16 = lane & 15, quad = lane >> 4;
  const int wr = wave >> 1, wc = wave & 1;

  for (int kt = 0; kt < D_MODEL / 64; ++kt) {
    const int k0 = kt * 64;
    stage_tile<128>(A + (size_t)m0 * D_MODEL + k0, D_MODEL, As, tid);
    stage_tile<128>(Bw + (size_t)e0 * D_MODEL + k0, D_MODEL, Bs, tid);
    __syncthreads();
#pragma unroll
    for (int ks = 0; ks < 2; ++ks) {
      bf16x8 af[4], bfr[4];
#pragma unroll
      for (int mi = 0; mi < 4; ++mi)
        af[mi] = *(const bf16x8*)(As + lds_off(wr * 64 + mi * 16 + l16, ks * 32 + quad * 8));
#pragma unroll
      for (int ci = 0; ci < 4; ++ci)
        bfr[ci] = *(const bf16x8*)(Bs + lds_off(wc * 64 + ci * 16 + l16, ks * 32 + quad * 8));
#pragma unroll
      for (int mi = 0; mi < 4; ++mi)
#pragma unroll
        for (int ci = 0; ci < 4; ++ci)
          acc[mi][ci] = __builtin_amdgcn_mfma_f32_16x16x32_bf16(af[mi], bfr[ci], acc[mi][ci], 0, 0, 0);
    }
    __syncthreads();
  }
}

// ---------------------------------------------------------------------------
// Fused Q/K/V projection. grid (32, 24): by -> {mat = by>>3, e0 = (by&7)*128}.
// mat 0 (q): LN epilogue with 0.125*log2e softmax/exp2 scale folded in.
// mat 1 (k): LN epilogue.
// mat 2 (v): V stored TRANSPOSED per (b,h), keys sigma-permuted within each
//            32-block so attn's in-register P^T fragment lines up with V.
// ---------------------------------------------------------------------------
__launch_bounds__(256)
__global__ void qkv_gemm(const unsigned short* __restrict__ xb,
                         const unsigned short* __restrict__ wb,   // wq|wk|wv bf16
                         const float* __restrict__ bq, const float* __restrict__ bk,
                         const float* __restrict__ bv,
                         const float* __restrict__ qg, const float* __restrict__ qbeta,
                         const float* __restrict__ kg, const float* __restrict__ kbeta,
                         unsigned short* __restrict__ qkout,      // qn | kn
                         unsigned short* __restrict__ vt) {
  __shared__ unsigned short As[128 * 64];
  __shared__ unsigned short Bs[128 * 64];
  const int m0  = blockIdx.x * 128;
  const int by  = blockIdx.y;
  const int mat = by >> 3;
  const int e0  = (by & 7) * 128;
  const unsigned short* Bw = wb + (size_t)mat * WEL;

  f32x4 acc[4][4];
#pragma unroll
  for (int mi = 0; mi < 4; ++mi)
#pragma unroll
    for (int ci = 0; ci < 4; ++ci) acc[mi][ci] = f32x4{0.f, 0.f, 0.f, 0.f};

  mainloop128(xb, Bw, m0, e0, As, Bs, acc);

  const int lane = threadIdx.x & 63, wave = threadIdx.x >> 6;
  const int l16 = lane & 15, quad = lane >> 4;
  const int wr = wave >> 1, wc = wave & 1;
  const int colbase = e0 + wc * 64;          // multiple of 64 -> one head per wave

  const float* bias = (mat == 0) ? bq : ((mat == 1) ? bk : bv);
  float bcol[4];
#pragma unroll
  for (int ci = 0; ci < 4; ++ci) bcol[ci] = bias[colbase + ci * 16 + l16];
#pragma unroll
  for (int mi = 0; mi < 4; ++mi)
#pragma unroll
    for (int ci = 0; ci < 4; ++ci)
#pragma unroll
      for (int r = 0; r < 4; ++r) acc[mi][ci][r] += bcol[ci];

  if (mat < 2) {
    const float* gamma = (mat == 0) ? qg : kg;
    const float* beta  = (mat == 0) ? qbeta : kbeta;
    // fold softmax scale AND log2(e) (attn uses exp2) into q
    const float sc = (mat == 0) ? 0.18033688011112042f : 1.0f;  // 0.125*log2e
    float g4[4], bt4[4];
#pragma unroll
    for (int ci = 0; ci < 4; ++ci) {
      g4[ci] = gamma[ci * 16 + l16] * sc;
      bt4[ci] = beta[ci * 16 + l16] * sc;
    }
#pragma unroll
    for (int mi = 0; mi < 4; ++mi)
#pragma unroll
      for (int r = 0; r < 4; ++r) {
        float s = acc[mi][0][r] + acc[mi][1][r] + acc[mi][2][r] + acc[mi][3][r];
        s += __shfl_xor(s, 1); s += __shfl_xor(s, 2);
        s += __shfl_xor(s, 4); s += __shfl_xor(s, 8);
        float mean = s * (1.f / 64.f);
        float d0 = acc[mi][0][r] - mean, d1 = acc[mi][1][r] - mean;
        float d2 = acc[mi][2][r] - mean, d3 = acc[mi][3][r] - mean;
        float q = d0 * d0 + d1 * d1 + d2 * d2 + d3 * d3;
        q += __shfl_xor(q, 1); q += __shfl_xor(q, 2);
        q += __shfl_xor(q, 4); q += __shfl_xor(q, 8);
        float rs = rsqrtf(q * (1.f / 64.f) + 1e-6f);
        acc[mi][0][r] = d0 * rs * g4[0] + bt4[0];
        acc[mi][1][r] = d1 * rs * g4[1] + bt4[1];
        acc[mi][2][r] = d2 * rs * g4[2] + bt4[2];
        acc[mi][3][r] = d3 * rs * g4[3] + bt4[3];
      }
    unsigned short* out = qkout + (size_t)mat * XEL;
#pragma unroll
    for (int mi = 0; mi < 4; ++mi)
#pragma unroll
      for (int ci = 0; ci < 4; ++ci) {
        int col = colbase + ci * 16 + l16;
#pragma unroll
        for (int r = 0; r < 4; ++r) {
          int row = m0 + wr * 64 + mi * 16 + quad * 4 + r;
          out[(size_t)row * D_MODEL + col] = f2bf(acc[mi][ci][r]);
        }
      }
  } else {
    // V transpose via wave-private LDS scratch (col-swizzled), then each lane
    // stores one full d-row (128B) as 8x dwordx4 -> coalesced.
    // Token index within 64 is sigma-permuted: logical t = 16*half+4*q+r
    // stored at phys = 8*q + 4*half + r (within its 32-block), matching the
    // attention kernel's in-register P^T bf16x8 fragment order.
    unsigned short* scr = ((wave < 2) ? As : Bs) + (size_t)(wave & 1) * 4096;
#pragma unroll
    for (int ci = 0; ci < 4; ++ci) {
      int dl = ci * 16 + l16;
      int sw = (dl & 3) * 16;
#pragma unroll
      for (int mi = 0; mi < 4; ++mi)
#pragma unroll
        for (int r = 0; r < 4; ++r) {
          // logical token t = mi*16 + quad*4 + r  (half = mi&1, block = mi>>1)
          int np = ((mi >> 1) << 5) + (quad << 3) + ((mi & 1) << 2) + r;
          scr[dl * 64 + (np ^ sw)] = f2bf(acc[mi][ci][r]);
        }
    }
    __builtin_amdgcn_wave_barrier();
    int row0 = m0 + wr * 64;                 // token base of this wave's tile
    int b = row0 >> 11, nb = row0 & 2047;
    int h = colbase >> 6;
    int dl = lane;                           // this lane's d within the head
    unsigned short* gdst = vt + ((size_t)((b * 16 + h) * 64 + dl) * N_SEQ + nb);
    const unsigned short* srow = scr + dl * 64;
    int sw = (dl & 3) * 16;
#pragma unroll
    for (int j = 0; j < 8; ++j) {
      uint4 vv = *(const uint4*)(srow + ((j * 8) ^ sw));
      *(uint4*)(gdst + j * 8) = vv;
    }
  }
}

// ---------------------------------------------------------------------------
// Output projection: fp32 out = ao * Wo^T + bo. grid (32, 8).
// ---------------------------------------------------------------------------
__launch_bounds__(256)
__global__ void out_gemm(const unsigned short* __restrict__ ao,
                         const unsigned short* __restrict__ wob,
                         const float* __restrict__ bo,
                         float* __restrict__ out) {
  __shared__ unsigned short As[128 * 64];
  __shared__ unsigned short Bs[128 * 64];
  const int m0 = blockIdx.x * 128;
  const int e0 = blockIdx.y * 128;

  f32x4 acc[4][4];
#pragma unroll
  for (int mi = 0; mi < 4; ++mi)
#pragma unroll
    for (int ci = 0; ci < 4; ++ci) acc[mi][ci] = f32x4{0.f, 0.f, 0.f, 0.f};

  mainloop128(ao, wob, m0, e0, As, Bs, acc);

  const int lane = threadIdx.x & 63, wave = threadIdx.x >> 6;
  const int l16 = lane & 15, quad = lane >> 4;
  const int wr = wave >> 1, wc = wave & 1;
  float bcol[4];
#pragma unroll
  for (int ci = 0; ci < 4; ++ci) bcol[ci] = bo[e0 + wc * 64 + ci * 16 + l16];
#pragma unroll
  for (int mi = 0; mi < 4; ++mi)
#pragma unroll
    for (int ci = 0; ci < 4; ++ci) {
      int col = e0 + wc * 64 + ci * 16 + l16;
#pragma unroll
      for (int r = 0; r < 4; ++r) {
        int row = m0 + wr * 64 + mi * 16 + quad * 4 + r;
        out[(size_t)row * D_MODEL + col] = acc[mi][ci][r] + bcol[ci];
      }
    }
}

// ---------------------------------------------------------------------------
// Flash attention, swapped-operand QK^T, 8 waves / 512 threads per block.
// Wave pair (2p, 2p+1) shares q-rows [p*32, p*32+32); wave 2p handles keys
// [0,32) of each 64-key tile, wave 2p+1 keys [32,64). This keeps the
// K/V-fragment reuse of the 4-wave version (8 b128 reads : 16 MFMA per wave
// per tile) while doubling occupancy to 4 waves/SIMD (LDS 48KB, grid 512 =
// 2 blocks/CU = 16 waves/CU) so dependency-chain stalls are filled by other
// waves. End-of-kernel: O/lsum pair-reduction through the (dead) LDS.
// No running max (LN'd q,k + |bias| bound -> exp2 safe).
// NOTE: LDS double-buffers selected by offset arithmetic, NOT pointer arrays
// (hipcc rejects shared-pointer-array initializers: addrspacecast error).
// ---------------------------------------------------------------------------
__launch_bounds__(512)
__global__ void attn_kernel(const unsigned short* __restrict__ Q,
                            const unsigned short* __restrict__ Kn,
                            const unsigned short* __restrict__ Vt,
                            const float* __restrict__ bias,
                            unsigned short* __restrict__ Out) {
  __shared__ unsigned short smem[24576];     // 48KB: Q(16K) | K dbuf(16K) | V dbuf(16K)
  unsigned short* Qs = smem;                 // 128*64

  const int tid  = threadIdx.x;
  const int wave = tid >> 6, lane = tid & 63;
  const int quad = lane >> 4, l16 = lane & 15;
  const int pairId = wave >> 1;              // 4 pairs x 32 q-rows
  const int kh = wave & 1;                   // key half of the 64-key tile
  const int bidx = blockIdx.x;
  const int qt = bidx & 15;                  // 16 q-tiles of 128
  const int h  = (bidx >> 4) & 15;
  const int b  = bidx >> 8;
  const int q0 = qt * 128;
  const size_t base  = (size_t)b * N_SEQ * D_MODEL + (size_t)h * 64;
  const unsigned short* vtb = Vt + (size_t)(b * 16 + h) * 64 * N_SEQ;

  // ---- stage Q (128 rows) + K/V tile 0 ----
  stage_tile<128, 512>(Q + base + (size_t)q0 * D_MODEL, D_MODEL, Qs, tid);
  stage_tile<64, 512>(Kn + base, D_MODEL, smem + 8192, tid);
  stage_tile<64, 512>(vtb, N_SEQ, smem + 16384, tid);

  // bias row pointers for this lane's q-rows (S^T layout: q = l16)
  const float* brow[2];
#pragma unroll
  for (int mi = 0; mi < 2; ++mi)
    brow[mi] = bias + ((size_t)b * N_SEQ + q0 + pairId * 32 + mi * 16 + l16) * N_SEQ;
  const int bcol0 = kh * 32 + quad * 4;      // this wave's key columns

  // double-buffered bias tile in regs: bcur = tile kt, bnxt = tile kt+1
  f32x4 bcur[2][2], bnxt[2][2];
#pragma unroll
  for (int mi = 0; mi < 2; ++mi)
#pragma unroll
    for (int cl = 0; cl < 2; ++cl)
      bcur[mi][cl] = *(const f32x4*)(brow[mi] + bcol0 + cl * 16);

  __syncthreads();
  bf16x8 aq[2][2];                           // [mi][ks] — shared by the pair
#pragma unroll
  for (int mi = 0; mi < 2; ++mi)
#pragma unroll
    for (int ks = 0; ks < 2; ++ks)
      aq[mi][ks] = *(const bf16x8*)(Qs + lds_off(pairId * 32 + mi * 16 + l16, ks * 32 + quad * 8));

  f32x4 o[2][4];                             // O^T partial: d = cd*16+quad*4+r, q = l16
#pragma unroll
  for (int mi = 0; mi < 2; ++mi)
#pragma unroll
    for (int cd = 0; cd < 4; ++cd) o[mi][cd] = f32x4{0.f, 0.f, 0.f, 0.f};
  float lsum[2] = {0.f, 0.f};
  constexpr float LOG2E = 1.44269504088896340736f;

  constexpr int NT = N_SEQ / 64;
  for (int kt = 0; kt < NT; ++kt) {
    const int cur = kt & 1;
    unsigned short* Kcur = smem + 8192 + cur * 4096;
    unsigned short* Vcur = smem + 16384 + cur * 4096;
    if (kt + 1 < NT) {                       // prefetch overlaps this tile
      stage_tile<64, 512>(Kn + base + (size_t)(kt + 1) * 64 * D_MODEL, D_MODEL,
                          smem + 8192 + (cur ^ 1) * 4096, tid);
      stage_tile<64, 512>(vtb + (kt + 1) * 64, N_SEQ,
                          smem + 16384 + (cur ^ 1) * 4096, tid);
#pragma unroll
      for (int mi = 0; mi < 2; ++mi)
#pragma unroll
        for (int cl = 0; cl < 2; ++cl)
          bnxt[mi][cl] = *(const f32x4*)(brow[mi] + (kt + 1) * 64 + bcol0 + cl * 16);
    }

    // S^T = K Q^T for this wave's 32 keys (q pre-scaled by 0.125*log2e)
    f32x4 sfT[2][2];                         // [mi][cl]: key = kh*32+cl*16+quad*4+r, q = l16
#pragma unroll
    for (int cl = 0; cl < 2; ++cl) {
      const int c = kh * 2 + cl;
      bf16x8 k0 = *(const bf16x8*)(Kcur + lds_off(c * 16 + l16, quad * 8));
      bf16x8 k1 = *(const bf16x8*)(Kcur + lds_off(c * 16 + l16, 32 + quad * 8));
#pragma unroll
      for (int mi = 0; mi < 2; ++mi) {
        f32x4 z = f32x4{0.f, 0.f, 0.f, 0.f};
        z = __builtin_amdgcn_mfma_f32_16x16x32_bf16(k0, aq[mi][0], z, 0, 0, 0);
        sfT[mi][cl] = __builtin_amdgcn_mfma_f32_16x16x32_bf16(k1, aq[mi][1], z, 0, 0, 0);
      }
    }

    // p = 2^(sT + bias*log2e); accumulate partial l; pack P^T to one bf16 frag
    // per mi (this wave's 32 keys), k-slot order matches sigma-permuted Vt.
    union PafU { unsigned int w[4]; bf16x8 v; };
    PafU paf[2];
#pragma unroll
    for (int mi = 0; mi < 2; ++mi)
#pragma unroll
      for (int cl = 0; cl < 2; ++cl) {
        float p0 = exp2fast(fmaf(bcur[mi][cl][0], LOG2E, sfT[mi][cl][0]));
        float p1 = exp2fast(fmaf(bcur[mi][cl][1], LOG2E, sfT[mi][cl][1]));
        float p2 = exp2fast(fmaf(bcur[mi][cl][2], LOG2E, sfT[mi][cl][2]));
        float p3 = exp2fast(fmaf(bcur[mi][cl][3], LOG2E, sfT[mi][cl][3]));
        lsum[mi] += (p0 + p1) + (p2 + p3);
        paf[mi].w[cl * 2]     = cvt_pk_bf16(p0, p1);
        paf[mi].w[cl * 2 + 1] = cvt_pk_bf16(p2, p3);
      }

    // O^T += V^T P^T over this wave's 32 keys (V frags reused across both mi)
    {
      bf16x8 bv[4];
#pragma unroll
      for (int cd = 0; cd < 4; ++cd)
        bv[cd] = *(const bf16x8*)(Vcur + lds_off(cd * 16 + l16, kh * 32 + quad * 8));
#pragma unroll
      for (int mi = 0; mi < 2; ++mi)
#pragma unroll
        for (int cd = 0; cd < 4; ++cd)
          o[mi][cd] = __builtin_amdgcn_mfma_f32_16x16x32_bf16(bv[cd], paf[mi].v, o[mi][cd], 0, 0, 0);
    }
    __syncthreads();   // all waves done with buf cur; prefetch cur^1 drained
#pragma unroll
    for (int mi = 0; mi < 2; ++mi)
#pragma unroll
      for (int cl = 0; cl < 2; ++cl) bcur[mi][cl] = bnxt[mi][cl];
  }

  // ---- pair reduction: odd wave dumps partial O + lsum to (dead) LDS ----
  float* red = (float*)smem;                 // 12288 floats available, need 8704
  float* slot = red + (size_t)(pairId * 64 + lane) * 34;
  if (kh) {
#pragma unroll
    for (int mi = 0; mi < 2; ++mi)
#pragma unroll
      for (int cd = 0; cd < 4; ++cd)
#pragma unroll
        for (int r = 0; r < 4; ++r)
          slot[mi * 16 + cd * 4 + r] = o[mi][cd][r];
    slot[32] = lsum[0];
    slot[33] = lsum[1];
  }
  __syncthreads();
  if (!kh) {
#pragma unroll
    for (int mi = 0; mi < 2; ++mi)
#pragma unroll
      for (int cd = 0; cd < 4; ++cd)
#pragma unroll
        for (int r = 0; r < 4; ++r)
          o[mi][cd][r] += slot[mi * 16 + cd * 4 + r];
    lsum[0] += slot[32];
    lsum[1] += slot[33];

    // normalize: lsum and O^T columns are both indexed by q = l16 -> lane-local
#pragma unroll
    for (int mi = 0; mi < 2; ++mi) {
      float l = lsum[mi];
      l += __shfl_xor(l, 16);
      l += __shfl_xor(l, 32);
      float inv = 1.0f / l;
      size_t row = (size_t)b * N_SEQ + q0 + pairId * 32 + mi * 16 + l16;
#pragma unroll
      for (int cd = 0; cd < 4; ++cd) {
        uint2 vv;
        vv.x = cvt_pk_bf16(o[mi][cd][0] * inv, o[mi][cd][1] * inv);
        vv.y = cvt_pk_bf16(o[mi][cd][2] * inv, o[mi][cd][3] * inv);
        *(uint2*)(Out + row * D_MODEL + h * 64 + cd * 16 + quad * 4) = vv;
      }
    }
  }
}

extern "C" void kernel_launch(void* const* d_in, const int* in_sizes, int n_in,
                              void* d_out, int out_size, void* d_ws, size_t ws_size,
                              hipStream_t stream) {
  const float* x    = (const float*)d_in[0];
  const float* bias = (const float*)d_in[1];
  const float* Wq = (const float*)d_in[2];  const float* bq = (const float*)d_in[3];
  const float* Wk = (const float*)d_in[4];  const float* bk = (const float*)d_in[5];
  const float* Wv = (const float*)d_in[6];  const float* bv = (const float*)d_in[7];
  const float* Wo = (const float*)d_in[8];  const float* bo = (const float*)d_in[9];
  const float* qg = (const float*)d_in[10]; const float* qb = (const float*)d_in[11];
  const float* kg = (const float*)d_in[12]; const float* kb = (const float*)d_in[13];
  float* out = (float*)d_out;

  unsigned short* wsb = (unsigned short*)d_ws;
  unsigned short* xb  = wsb;                 // 4M (reused as ao after qkv_gemm)
  unsigned short* wqb = wsb + XEL;           // 4 x 1M weights
  unsigned short* wob = wsb + XEL + 3 * WEL;
  unsigned short* qn  = wsb + XEL + 4 * WEL; // 4M
  unsigned short* kn  = qn + XEL;            // 4M
  unsigned short* vt  = qn + 2 * XEL;        // 4M, transposed + key-permuted
  unsigned short* ao  = xb;                  // alias: xb dead after qkv_gemm

  dim3 blk(256, 1, 1);

  cvt_kernel<<<dim3((unsigned)((XEL + 4 * WEL) / (256 * 8)), 1, 1), blk, 0, stream>>>(
      x, Wq, Wk, Wv, Wo, wsb);

  qkv_gemm<<<dim3(M_ROWS / 128, 24, 1), blk, 0, stream>>>(
      xb, wqb, bq, bk, bv, qg, qb, kg, kb, qn, vt);

  attn_kernel<<<dim3(N_B * 16 * (N_SEQ / 128), 1, 1), dim3(512, 1, 1), 0, stream>>>(
      qn, kn, vt, bias, ao);

  out_gemm<<<dim3(M_ROWS / 128, D_MODEL / 128, 1), blk, 0, stream>>>(ao, wob, bo, out);
}

// Round 4
// 258.562 us; speedup vs baseline: 1.0775x; 1.0020x over previous
//
#include <hip/hip_runtime.h>
#include <hip/hip_bf16.h>

#define D_MODEL 1024
#define N_SEQ   2048
#define N_B     2
#define M_ROWS  (N_B * N_SEQ)   // 4096

typedef __attribute__((ext_vector_type(8))) short bf16x8;
typedef __attribute__((ext_vector_type(4))) float f32x4;

typedef const __attribute__((address_space(1))) unsigned int gu32_t;
typedef __attribute__((address_space(3))) unsigned int lu32_t;

__device__ __forceinline__ void gload16(const void* g, void* l) {
  // async global->LDS, 16B per lane; LDS dest = wave-uniform base + lane*16
  __builtin_amdgcn_global_load_lds((gu32_t*)g, (lu32_t*)l, 16, 0, 0);
}

__device__ inline unsigned short f2bf(float f) {
  union { float f; unsigned int u; } v; v.f = f;
  unsigned int r = (v.u + 0x7FFFu + ((v.u >> 16) & 1u)) >> 16;
  return (unsigned short)r;
}

// packed f32x2 -> bf16x2 (RNE); no builtin on gfx950, per learn_hip m240
__device__ __forceinline__ unsigned int cvt_pk_bf16(float a, float b) {
  unsigned int r;
  asm("v_cvt_pk_bf16_f32 %0, %1, %2" : "=v"(r) : "v"(a), "v"(b));
  return r;
}

__device__ __forceinline__ float exp2fast(float x) {
#if __has_builtin(__builtin_amdgcn_exp2f)
  return __builtin_amdgcn_exp2f(x);
#else
  return __expf(x * 0.69314718056f);
#endif
}

// counted vmcnt wait (T4): never drain to 0 in the main loop
#define WAITV(N) asm volatile("s_waitcnt vmcnt(" #N ")" ::: "memory")

// Bank-conflict swizzle for 64-col (128B-row) LDS tiles:
// logical 16B-chunk k of row r lives at physical chunk k ^ (r & 7).
__device__ __forceinline__ int lds_off(int row, int col /*ushort idx*/) {
  return row * 64 + (((col >> 3) ^ (row & 7)) << 3) + (col & 7);
}

// Stage a ROWS x 64-ushort tile global->LDS with the swizzle applied on the
// global-source side (LDS destination must stay linear for global_load_lds).
template<int ROWS, int NTHR = 256>
__device__ __forceinline__ void stage_tile(const unsigned short* gbase, size_t gstride,
                                           unsigned short* lds, int tid) {
  const int wave = tid >> 6;
#pragma unroll
  for (int rnd = 0; rnd < ROWS * 8 / NTHR; ++rnd) {
    int c = rnd * NTHR + tid;
    int row = c >> 3, pc = c & 7;
    int gcol = ((pc ^ (row & 7)) << 3);
    gload16(gbase + (size_t)row * gstride + gcol,
            lds + (size_t)(rnd * NTHR + wave * 64) * 8);
  }
}

constexpr size_t XEL = (size_t)M_ROWS * D_MODEL;     // 4194304
constexpr size_t WEL = (size_t)D_MODEL * D_MODEL;    // 1048576

// ---------------------------------------------------------------------------
// fp32 -> bf16 convert for [x (4M) | Wq | Wk | Wv | Wo (1M each)] -> ws
// ---------------------------------------------------------------------------
__launch_bounds__(256)
__global__ void cvt_kernel(const float* __restrict__ x,
                           const float* __restrict__ wq, const float* __restrict__ wk,
                           const float* __restrict__ wv, const float* __restrict__ wo,
                           unsigned short* __restrict__ dst) {
  size_t i = ((size_t)blockIdx.x * 256 + threadIdx.x) * 8;
  if (i >= XEL + 4 * WEL) return;
  const float* s; size_t off = i;
  if (off < XEL)                { s = x; }
  else if (off < XEL + WEL)     { s = wq; off -= XEL; }
  else if (off < XEL + 2*WEL)   { s = wk; off -= XEL + WEL; }
  else if (off < XEL + 3*WEL)   { s = wv; off -= XEL + 2*WEL; }
  else                          { s = wo; off -= XEL + 3*WEL; }
  float4 f0 = *(const float4*)(s + off);
  float4 f1 = *(const float4*)(s + off + 4);
  unsigned short t[8] = { f2bf(f0.x), f2bf(f0.y), f2bf(f0.z), f2bf(f0.w),
                          f2bf(f1.x), f2bf(f1.y), f2bf(f1.z), f2bf(f1.w) };
  *(uint4*)(dst + i) = *(const uint4*)t;
}

// ---------------------------------------------------------------------------
// m97-style 128x128 bf16 mainloop, swizzled LDS: C = A * Bw^T
// ---------------------------------------------------------------------------
__device__ __forceinline__ void mainloop128(const unsigned short* __restrict__ A,
                                            const unsigned short* __restrict__ Bw,
                                            int m0, int e0,
                                            unsigned short* As, unsigned short* Bs,
                                            f32x4 (&acc)[4][4]) {
  const int tid  = threadIdx.x;
  const int wave = tid >> 6, lane = tid & 63;
  const int l16 = lane & 15, quad = lane >> 4;
  const int wr = wave >> 1, wc = wave & 1;

  for (int kt = 0; kt < D_MODEL / 64; ++kt) {
    const int k0 = kt * 64;
    stage_tile<128>(A + (size_t)m0 * D_MODEL + k0, D_MODEL, As, tid);
    stage_tile<128>(Bw + (size_t)e0 * D_MODEL + k0, D_MODEL, Bs, tid);
    __syncthreads();
#pragma unroll
    for (int ks = 0; ks < 2; ++ks) {
      bf16x8 af[4], bfr[4];
#pragma unroll
      for (int mi = 0; mi < 4; ++mi)
        af[mi] = *(const bf16x8*)(As + lds_off(wr * 64 + mi * 16 + l16, ks * 32 + quad * 8));
#pragma unroll
      for (int ci = 0; ci < 4; ++ci)
        bfr[ci] = *(const bf16x8*)(Bs + lds_off(wc * 64 + ci * 16 + l16, ks * 32 + quad * 8));
#pragma unroll
      for (int mi = 0; mi < 4; ++mi)
#pragma unroll
        for (int ci = 0; ci < 4; ++ci)
          acc[mi][ci] = __builtin_amdgcn_mfma_f32_16x16x32_bf16(af[mi], bfr[ci], acc[mi][ci], 0, 0, 0);
    }
    __syncthreads();
  }
}

// ---------------------------------------------------------------------------
// Fused Q/K/V projection. grid (32, 24): by -> {mat = by>>3, e0 = (by&7)*128}.
// mat 0 (q): LN epilogue with 0.125*log2e softmax/exp2 scale folded in.
// mat 1 (k): LN epilogue.
// mat 2 (v): V stored TRANSPOSED per (b,h), keys sigma-permuted within each
//            32-block so attn's in-register P^T fragment lines up with V.
// ---------------------------------------------------------------------------
__launch_bounds__(256)
__global__ void qkv_gemm(const unsigned short* __restrict__ xb,
                         const unsigned short* __restrict__ wb,   // wq|wk|wv bf16
                         const float* __restrict__ bq, const float* __restrict__ bk,
                         const float* __restrict__ bv,
                         const float* __restrict__ qg, const float* __restrict__ qbeta,
                         const float* __restrict__ kg, const float* __restrict__ kbeta,
                         unsigned short* __restrict__ qkout,      // qn | kn
                         unsigned short* __restrict__ vt) {
  __shared__ unsigned short As[128 * 64];
  __shared__ unsigned short Bs[128 * 64];
  const int m0  = blockIdx.x * 128;
  const int by  = blockIdx.y;
  const int mat = by >> 3;
  const int e0  = (by & 7) * 128;
  const unsigned short* Bw = wb + (size_t)mat * WEL;

  f32x4 acc[4][4];
#pragma unroll
  for (int mi = 0; mi < 4; ++mi)
#pragma unroll
    for (int ci = 0; ci < 4; ++ci) acc[mi][ci] = f32x4{0.f, 0.f, 0.f, 0.f};

  mainloop128(xb, Bw, m0, e0, As, Bs, acc);

  const int lane = threadIdx.x & 63, wave = threadIdx.x >> 6;
  const int l16 = lane & 15, quad = lane >> 4;
  const int wr = wave >> 1, wc = wave & 1;
  const int colbase = e0 + wc * 64;          // multiple of 64 -> one head per wave

  const float* bias = (mat == 0) ? bq : ((mat == 1) ? bk : bv);
  float bcol[4];
#pragma unroll
  for (int ci = 0; ci < 4; ++ci) bcol[ci] = bias[colbase + ci * 16 + l16];
#pragma unroll
  for (int mi = 0; mi < 4; ++mi)
#pragma unroll
    for (int ci = 0; ci < 4; ++ci)
#pragma unroll
      for (int r = 0; r < 4; ++r) acc[mi][ci][r] += bcol[ci];

  if (mat < 2) {
    const float* gamma = (mat == 0) ? qg : kg;
    const float* beta  = (mat == 0) ? qbeta : kbeta;
    // fold softmax scale AND log2(e) (attn uses exp2) into q
    const float sc = (mat == 0) ? 0.18033688011112042f : 1.0f;  // 0.125*log2e
    float g4[4], bt4[4];
#pragma unroll
    for (int ci = 0; ci < 4; ++ci) {
      g4[ci] = gamma[ci * 16 + l16] * sc;
      bt4[ci] = beta[ci * 16 + l16] * sc;
    }
#pragma unroll
    for (int mi = 0; mi < 4; ++mi)
#pragma unroll
      for (int r = 0; r < 4; ++r) {
        float s = acc[mi][0][r] + acc[mi][1][r] + acc[mi][2][r] + acc[mi][3][r];
        s += __shfl_xor(s, 1); s += __shfl_xor(s, 2);
        s += __shfl_xor(s, 4); s += __shfl_xor(s, 8);
        float mean = s * (1.f / 64.f);
        float d0 = acc[mi][0][r] - mean, d1 = acc[mi][1][r] - mean;
        float d2 = acc[mi][2][r] - mean, d3 = acc[mi][3][r] - mean;
        float q = d0 * d0 + d1 * d1 + d2 * d2 + d3 * d3;
        q += __shfl_xor(q, 1); q += __shfl_xor(q, 2);
        q += __shfl_xor(q, 4); q += __shfl_xor(q, 8);
        float rs = rsqrtf(q * (1.f / 64.f) + 1e-6f);
        acc[mi][0][r] = d0 * rs * g4[0] + bt4[0];
        acc[mi][1][r] = d1 * rs * g4[1] + bt4[1];
        acc[mi][2][r] = d2 * rs * g4[2] + bt4[2];
        acc[mi][3][r] = d3 * rs * g4[3] + bt4[3];
      }
    unsigned short* out = qkout + (size_t)mat * XEL;
#pragma unroll
    for (int mi = 0; mi < 4; ++mi)
#pragma unroll
      for (int ci = 0; ci < 4; ++ci) {
        int col = colbase + ci * 16 + l16;
#pragma unroll
        for (int r = 0; r < 4; ++r) {
          int row = m0 + wr * 64 + mi * 16 + quad * 4 + r;
          out[(size_t)row * D_MODEL + col] = f2bf(acc[mi][ci][r]);
        }
      }
  } else {
    // V transpose via wave-private LDS scratch (col-swizzled), then each lane
    // stores one full d-row (128B) as 8x dwordx4 -> coalesced.
    // Token index within 64 is sigma-permuted: logical t = 16*half+4*q+r
    // stored at phys = 8*q + 4*half + r (within its 32-block), matching the
    // attention kernel's in-register P^T bf16x8 fragment order.
    unsigned short* scr = ((wave < 2) ? As : Bs) + (size_t)(wave & 1) * 4096;
#pragma unroll
    for (int ci = 0; ci < 4; ++ci) {
      int dl = ci * 16 + l16;
      int sw = (dl & 3) * 16;
#pragma unroll
      for (int mi = 0; mi < 4; ++mi)
#pragma unroll
        for (int r = 0; r < 4; ++r) {
          // logical token t = mi*16 + quad*4 + r  (half = mi&1, block = mi>>1)
          int np = ((mi >> 1) << 5) + (quad << 3) + ((mi & 1) << 2) + r;
          scr[dl * 64 + (np ^ sw)] = f2bf(acc[mi][ci][r]);
        }
    }
    __builtin_amdgcn_wave_barrier();
    int row0 = m0 + wr * 64;                 // token base of this wave's tile
    int b = row0 >> 11, nb = row0 & 2047;
    int h = colbase >> 6;
    int dl = lane;                           // this lane's d within the head
    unsigned short* gdst = vt + ((size_t)((b * 16 + h) * 64 + dl) * N_SEQ + nb);
    const unsigned short* srow = scr + dl * 64;
    int sw = (dl & 3) * 16;
#pragma unroll
    for (int j = 0; j < 8; ++j) {
      uint4 vv = *(const uint4*)(srow + ((j * 8) ^ sw));
      *(uint4*)(gdst + j * 8) = vv;
    }
  }
}

// ---------------------------------------------------------------------------
// Output projection: fp32 out = ao * Wo^T + bo. grid (32, 8).
// ---------------------------------------------------------------------------
__launch_bounds__(256)
__global__ void out_gemm(const unsigned short* __restrict__ ao,
                         const unsigned short* __restrict__ wob,
                         const float* __restrict__ bo,
                         float* __restrict__ out) {
  __shared__ unsigned short As[128 * 64];
  __shared__ unsigned short Bs[128 * 64];
  const int m0 = blockIdx.x * 128;
  const int e0 = blockIdx.y * 128;

  f32x4 acc[4][4];
#pragma unroll
  for (int mi = 0; mi < 4; ++mi)
#pragma unroll
    for (int ci = 0; ci < 4; ++ci) acc[mi][ci] = f32x4{0.f, 0.f, 0.f, 0.f};

  mainloop128(ao, wob, m0, e0, As, Bs, acc);

  const int lane = threadIdx.x & 63, wave = threadIdx.x >> 6;
  const int l16 = lane & 15, quad = lane >> 4;
  const int wr = wave >> 1, wc = wave & 1;
  float bcol[4];
#pragma unroll
  for (int ci = 0; ci < 4; ++ci) bcol[ci] = bo[e0 + wc * 64 + ci * 16 + l16];
#pragma unroll
  for (int mi = 0; mi < 4; ++mi)
#pragma unroll
    for (int ci = 0; ci < 4; ++ci) {
      int col = e0 + wc * 64 + ci * 16 + l16;
#pragma unroll
      for (int r = 0; r < 4; ++r) {
        int row = m0 + wr * 64 + mi * 16 + quad * 4 + r;
        out[(size_t)row * D_MODEL + col] = acc[mi][ci][r] + bcol[ci];
      }
    }
}

// ---------------------------------------------------------------------------
// Flash attention, swapped-operand QK^T, 8 waves / 512 threads per block.
// Wave pair (2p, 2p+1): wave 2p keys [0,32), wave 2p+1 keys [32,64) of the
// shared q-rows [p*32, p*32+32).
// R4: depth-3 circular K/V LDS buffers + COUNTED vmcnt + raw s_barrier (T3/T4)
// — iteration kt stages tile kt+2, reads tile kt; the stage DMA stays in
// flight ~2 iterations instead of being drained by __syncthreads' implicit
// vmcnt(0) every tile. Bias loads are issued BEFORE the stage ops so the
// compiler's implicit wait on bias consumption (in-order vmcnt retirement)
// never forces the freshest stage. vmcnt(6) = this iter's bias(4)+stage(2)
// newer than the tile-kt+1 stage we must guarantee before the barrier.
// LDS 64KB: Q 16K | K 3x8K | V 3x8K -> still 2 blocks/CU (128KB <= 160KB).
// ---------------------------------------------------------------------------
__launch_bounds__(512)
__global__ void attn_kernel(const unsigned short* __restrict__ Q,
                            const unsigned short* __restrict__ Kn,
                            const unsigned short* __restrict__ Vt,
                            const float* __restrict__ bias,
                            unsigned short* __restrict__ Out) {
  __shared__ unsigned short smem[32768];     // 64KB
  unsigned short* Qs = smem;                 // [0, 8192): 128*64
  // K bufs: smem + 8192 + i*4096, i=0..2 ; V bufs: smem + 20480 + i*4096

  const int tid  = threadIdx.x;
  const int wave = tid >> 6, lane = tid & 63;
  const int quad = lane >> 4, l16 = lane & 15;
  const int pairId = wave >> 1;              // 4 pairs x 32 q-rows
  const int kh = wave & 1;                   // key half of the 64-key tile
  const int bidx = blockIdx.x;
  const int qt = bidx & 15;                  // 16 q-tiles of 128
  const int h  = (bidx >> 4) & 15;
  const int b  = bidx >> 8;
  const int q0 = qt * 128;
  const size_t base  = (size_t)b * N_SEQ * D_MODEL + (size_t)h * 64;
  const unsigned short* vtb = Vt + (size_t)(b * 16 + h) * 64 * N_SEQ;

  // bias row pointers for this lane's q-rows (S^T layout: q = l16)
  const float* brow[2];
#pragma unroll
  for (int mi = 0; mi < 2; ++mi)
    brow[mi] = bias + ((size_t)b * N_SEQ + q0 + pairId * 32 + mi * 16 + l16) * N_SEQ;
  const int bcol0 = kh * 32 + quad * 4;      // this wave's key columns

  // ---- prologue: stage Q + tiles 0,1; bias tile 0 ----
  stage_tile<128, 512>(Q + base + (size_t)q0 * D_MODEL, D_MODEL, Qs, tid);

  f32x4 bcur[2][2], bnxt[2][2];
#pragma unroll
  for (int mi = 0; mi < 2; ++mi)
#pragma unroll
    for (int cl = 0; cl < 2; ++cl)
      bcur[mi][cl] = *(const f32x4*)(brow[mi] + bcol0 + cl * 16);

  stage_tile<64, 512>(Kn + base, D_MODEL, smem + 8192, tid);
  stage_tile<64, 512>(vtb, N_SEQ, smem + 20480, tid);
  stage_tile<64, 512>(Kn + base + (size_t)64 * D_MODEL, D_MODEL, smem + 8192 + 4096, tid);
  stage_tile<64, 512>(vtb + 64, N_SEQ, smem + 20480 + 4096, tid);

  WAITV(2);                                  // Q + tile0 done; tile1 in flight
  __builtin_amdgcn_s_barrier();
  __builtin_amdgcn_sched_barrier(0);

  bf16x8 aq[2][2];                           // [mi][ks] — shared by the pair
#pragma unroll
  for (int mi = 0; mi < 2; ++mi)
#pragma unroll
    for (int ks = 0; ks < 2; ++ks)
      aq[mi][ks] = *(const bf16x8*)(Qs + lds_off(pairId * 32 + mi * 16 + l16, ks * 32 + quad * 8));

  f32x4 o[2][4];                             // O^T partial: d = cd*16+quad*4+r, q = l16
#pragma unroll
  for (int mi = 0; mi < 2; ++mi)
#pragma unroll
    for (int cd = 0; cd < 4; ++cd) o[mi][cd] = f32x4{0.f, 0.f, 0.f, 0.f};
  float lsum[2] = {0.f, 0.f};
  constexpr float LOG2E = 1.44269504088896340736f;

  constexpr int NT = N_SEQ / 64;
  for (int kt = 0; kt < NT; ++kt) {
    const int cur = kt % 3;
    unsigned short* Kcur = smem + 8192 + cur * 4096;
    unsigned short* Vcur = smem + 20480 + cur * 4096;

    // bias for kt+1 FIRST (issue order matters for in-order vmcnt retirement)
    if (kt + 1 < NT) {
#pragma unroll
      for (int mi = 0; mi < 2; ++mi)
#pragma unroll
        for (int cl = 0; cl < 2; ++cl)
          bnxt[mi][cl] = *(const f32x4*)(brow[mi] + (kt + 1) * 64 + bcol0 + cl * 16);
    }
    // stage tile kt+2 into buf (kt+2)%3 (read last at iteration kt-1;
    // the barrier at end of kt-1 made it safe to overwrite)
    if (kt + 2 < NT) {
      const int nb = (kt + 2) % 3;
      stage_tile<64, 512>(Kn + base + (size_t)(kt + 2) * 64 * D_MODEL, D_MODEL,
                          smem + 8192 + nb * 4096, tid);
      stage_tile<64, 512>(vtb + (kt + 2) * 64, N_SEQ,
                          smem + 20480 + nb * 4096, tid);
    }

    // S^T = K Q^T for this wave's 32 keys (q pre-scaled by 0.125*log2e)
    f32x4 sfT[2][2];                         // [mi][cl]: key = kh*32+cl*16+quad*4+r, q = l16
#pragma unroll
    for (int cl = 0; cl < 2; ++cl) {
      const int c = kh * 2 + cl;
      bf16x8 k0 = *(const bf16x8*)(Kcur + lds_off(c * 16 + l16, quad * 8));
      bf16x8 k1 = *(const bf16x8*)(Kcur + lds_off(c * 16 + l16, 32 + quad * 8));
#pragma unroll
      for (int mi = 0; mi < 2; ++mi) {
        f32x4 z = f32x4{0.f, 0.f, 0.f, 0.f};
        z = __builtin_amdgcn_mfma_f32_16x16x32_bf16(k0, aq[mi][0], z, 0, 0, 0);
        sfT[mi][cl] = __builtin_amdgcn_mfma_f32_16x16x32_bf16(k1, aq[mi][1], z, 0, 0, 0);
      }
    }

    // p = 2^(sT + bias*log2e); accumulate partial l; pack P^T to one bf16 frag
    // per mi (this wave's 32 keys), k-slot order matches sigma-permuted Vt.
    union PafU { unsigned int w[4]; bf16x8 v; };
    PafU paf[2];
#pragma unroll
    for (int mi = 0; mi < 2; ++mi)
#pragma unroll
      for (int cl = 0; cl < 2; ++cl) {
        float p0 = exp2fast(fmaf(bcur[mi][cl][0], LOG2E, sfT[mi][cl][0]));
        float p1 = exp2fast(fmaf(bcur[mi][cl][1], LOG2E, sfT[mi][cl][1]));
        float p2 = exp2fast(fmaf(bcur[mi][cl][2], LOG2E, sfT[mi][cl][2]));
        float p3 = exp2fast(fmaf(bcur[mi][cl][3], LOG2E, sfT[mi][cl][3]));
        lsum[mi] += (p0 + p1) + (p2 + p3);
        paf[mi].w[cl * 2]     = cvt_pk_bf16(p0, p1);
        paf[mi].w[cl * 2 + 1] = cvt_pk_bf16(p2, p3);
      }

    // O^T += V^T P^T over this wave's 32 keys (V frags reused across both mi)
    {
      bf16x8 bv[4];
#pragma unroll
      for (int cd = 0; cd < 4; ++cd)
        bv[cd] = *(const bf16x8*)(Vcur + lds_off(cd * 16 + l16, kh * 32 + quad * 8));
#pragma unroll
      for (int mi = 0; mi < 2; ++mi)
#pragma unroll
        for (int cd = 0; cd < 4; ++cd)
          o[mi][cd] = __builtin_amdgcn_mfma_f32_16x16x32_bf16(bv[cd], paf[mi].v, o[mi][cd], 0, 0, 0);
    }

#pragma unroll
    for (int mi = 0; mi < 2; ++mi)
#pragma unroll
      for (int cl = 0; cl < 2; ++cl) bcur[mi][cl] = bnxt[mi][cl];

    // counted wait: guarantee tile kt+1 (staged at kt-1) landed, leave this
    // iteration's bias(4)+stage(2) in flight; raw barrier (no vmcnt(0) drain)
    if (kt + 1 < NT) {
      if (kt < NT - 2) { WAITV(6); } else { WAITV(4); }
      __builtin_amdgcn_s_barrier();
      __builtin_amdgcn_sched_barrier(0);
    }
  }

  // drain any stragglers before reusing K-buffer LDS as reduction scratch
  WAITV(0);
  __syncthreads();

  // ---- pair reduction: odd wave dumps partial O + lsum to (dead) LDS ----
  float* red = (float*)smem;                 // need 8704 floats = 34816B < 64KB
  float* slot = red + (size_t)(pairId * 64 + lane) * 34;
  if (kh) {
#pragma unroll
    for (int mi = 0; mi < 2; ++mi)
#pragma unroll
      for (int cd = 0; cd < 4; ++cd)
#pragma unroll
        for (int r = 0; r < 4; ++r)
          slot[mi * 16 + cd * 4 + r] = o[mi][cd][r];
    slot[32] = lsum[0];
    slot[33] = lsum[1];
  }
  __syncthreads();
  if (!kh) {
#pragma unroll
    for (int mi = 0; mi < 2; ++mi)
#pragma unroll
      for (int cd = 0; cd < 4; ++cd)
#pragma unroll
        for (int r = 0; r < 4; ++r)
          o[mi][cd][r] += slot[mi * 16 + cd * 4 + r];
    lsum[0] += slot[32];
    lsum[1] += slot[33];

    // normalize: lsum and O^T columns are both indexed by q = l16 -> lane-local
#pragma unroll
    for (int mi = 0; mi < 2; ++mi) {
      float l = lsum[mi];
      l += __shfl_xor(l, 16);
      l += __shfl_xor(l, 32);
      float inv = 1.0f / l;
      size_t row = (size_t)b * N_SEQ + q0 + pairId * 32 + mi * 16 + l16;
#pragma unroll
      for (int cd = 0; cd < 4; ++cd) {
        uint2 vv;
        vv.x = cvt_pk_bf16(o[mi][cd][0] * inv, o[mi][cd][1] * inv);
        vv.y = cvt_pk_bf16(o[mi][cd][2] * inv, o[mi][cd][3] * inv);
        *(uint2*)(Out + row * D_MODEL + h * 64 + cd * 16 + quad * 4) = vv;
      }
    }
  }
}

extern "C" void kernel_launch(void* const* d_in, const int* in_sizes, int n_in,
                              void* d_out, int out_size, void* d_ws, size_t ws_size,
                              hipStream_t stream) {
  const float* x    = (const float*)d_in[0];
  const float* bias = (const float*)d_in[1];
  const float* Wq = (const float*)d_in[2];  const float* bq = (const float*)d_in[3];
  const float* Wk = (const float*)d_in[4];  const float* bk = (const float*)d_in[5];
  const float* Wv = (const float*)d_in[6];  const float* bv = (const float*)d_in[7];
  const float* Wo = (const float*)d_in[8];  const float* bo = (const float*)d_in[9];
  const float* qg = (const float*)d_in[10]; const float* qb = (const float*)d_in[11];
  const float* kg = (const float*)d_in[12]; const float* kb = (const float*)d_in[13];
  float* out = (float*)d_out;

  unsigned short* wsb = (unsigned short*)d_ws;
  unsigned short* xb  = wsb;                 // 4M (reused as ao after qkv_gemm)
  unsigned short* wqb = wsb + XEL;           // 4 x 1M weights
  unsigned short* wob = wsb + XEL + 3 * WEL;
  unsigned short* qn  = wsb + XEL + 4 * WEL; // 4M
  unsigned short* kn  = qn + XEL;            // 4M
  unsigned short* vt  = qn + 2 * XEL;        // 4M, transposed + key-permuted
  unsigned short* ao  = xb;                  // alias: xb dead after qkv_gemm

  dim3 blk(256, 1, 1);

  cvt_kernel<<<dim3((unsigned)((XEL + 4 * WEL) / (256 * 8)), 1, 1), blk, 0, stream>>>(
      x, Wq, Wk, Wv, Wo, wsb);

  qkv_gemm<<<dim3(M_ROWS / 128, 24, 1), blk, 0, stream>>>(
      xb, wqb, bq, bk, bv, qg, qb, kg, kb, qn, vt);

  attn_kernel<<<dim3(N_B * 16 * (N_SEQ / 128), 1, 1), dim3(512, 1, 1), 0, stream>>>(
      qn, kn, vt, bias, ao);

  out_gemm<<<dim3(M_ROWS / 128, D_MODEL / 128, 1), blk, 0, stream>>>(ao, wob, bo, out);
}

// Round 5
// 256.958 us; speedup vs baseline: 1.0842x; 1.0062x over previous
//
#include <hip/hip_runtime.h>
#include <hip/hip_bf16.h>

#define D_MODEL 1024
#define N_SEQ   2048
#define N_B     2
#define M_ROWS  (N_B * N_SEQ)   // 4096

typedef __attribute__((ext_vector_type(8))) short bf16x8;
typedef __attribute__((ext_vector_type(4))) float f32x4;

typedef const __attribute__((address_space(1))) unsigned int gu32_t;
typedef __attribute__((address_space(3))) unsigned int lu32_t;

__device__ __forceinline__ void gload16(const void* g, void* l) {
  // async global->LDS, 16B per lane; LDS dest = wave-uniform base + lane*16
  __builtin_amdgcn_global_load_lds((gu32_t*)g, (lu32_t*)l, 16, 0, 0);
}

__device__ inline unsigned short f2bf(float f) {
  union { float f; unsigned int u; } v; v.f = f;
  unsigned int r = (v.u + 0x7FFFu + ((v.u >> 16) & 1u)) >> 16;
  return (unsigned short)r;
}

// packed f32x2 -> bf16x2 (RNE); no builtin on gfx950, per learn_hip m240
__device__ __forceinline__ unsigned int cvt_pk_bf16(float a, float b) {
  unsigned int r;
  asm("v_cvt_pk_bf16_f32 %0, %1, %2" : "=v"(r) : "v"(a), "v"(b));
  return r;
}

__device__ __forceinline__ float exp2fast(float x) {
#if __has_builtin(__builtin_amdgcn_exp2f)
  return __builtin_amdgcn_exp2f(x);
#else
  return __expf(x * 0.69314718056f);
#endif
}

// counted vmcnt wait (T4): never drain to 0 in the main loop
#define WAITV(N) asm volatile("s_waitcnt vmcnt(" #N ")" ::: "memory")

// Bank-conflict swizzle for 64-col (128B-row) LDS tiles:
// logical 16B-chunk k of row r lives at physical chunk k ^ (r & 7).
__device__ __forceinline__ int lds_off(int row, int col /*ushort idx*/) {
  return row * 64 + (((col >> 3) ^ (row & 7)) << 3) + (col & 7);
}

// Stage a ROWS x 64-ushort tile global->LDS with the swizzle applied on the
// global-source side (LDS destination must stay linear for global_load_lds).
template<int ROWS, int NTHR = 256>
__device__ __forceinline__ void stage_tile(const unsigned short* gbase, size_t gstride,
                                           unsigned short* lds, int tid) {
  const int wave = tid >> 6;
#pragma unroll
  for (int rnd = 0; rnd < ROWS * 8 / NTHR; ++rnd) {
    int c = rnd * NTHR + tid;
    int row = c >> 3, pc = c & 7;
    int gcol = ((pc ^ (row & 7)) << 3);
    gload16(gbase + (size_t)row * gstride + gcol,
            lds + (size_t)(rnd * NTHR + wave * 64) * 8);
  }
}

constexpr size_t XEL = (size_t)M_ROWS * D_MODEL;     // 4194304
constexpr size_t WEL = (size_t)D_MODEL * D_MODEL;    // 1048576

// ---------------------------------------------------------------------------
// fp32 -> bf16 convert for [x (4M) | Wq | Wk | Wv | Wo (1M each)] -> ws
// ---------------------------------------------------------------------------
__launch_bounds__(256)
__global__ void cvt_kernel(const float* __restrict__ x,
                           const float* __restrict__ wq, const float* __restrict__ wk,
                           const float* __restrict__ wv, const float* __restrict__ wo,
                           unsigned short* __restrict__ dst) {
  size_t i = ((size_t)blockIdx.x * 256 + threadIdx.x) * 8;
  if (i >= XEL + 4 * WEL) return;
  const float* s; size_t off = i;
  if (off < XEL)                { s = x; }
  else if (off < XEL + WEL)     { s = wq; off -= XEL; }
  else if (off < XEL + 2*WEL)   { s = wk; off -= XEL + WEL; }
  else if (off < XEL + 3*WEL)   { s = wv; off -= XEL + 2*WEL; }
  else                          { s = wo; off -= XEL + 3*WEL; }
  float4 f0 = *(const float4*)(s + off);
  float4 f1 = *(const float4*)(s + off + 4);
  unsigned short t[8] = { f2bf(f0.x), f2bf(f0.y), f2bf(f0.z), f2bf(f0.w),
                          f2bf(f1.x), f2bf(f1.y), f2bf(f1.z), f2bf(f1.w) };
  *(uint4*)(dst + i) = *(const uint4*)t;
}

// ---------------------------------------------------------------------------
// m97-style 128x128 bf16 mainloop, swizzled LDS: C = A * Bw^T
// ---------------------------------------------------------------------------
__device__ __forceinline__ void mainloop128(const unsigned short* __restrict__ A,
                                            const unsigned short* __restrict__ Bw,
                                            int m0, int e0,
                                            unsigned short* As, unsigned short* Bs,
                                            f32x4 (&acc)[4][4]) {
  const int tid  = threadIdx.x;
  const int wave = tid >> 6, lane = tid & 63;
  const int l16 = lane & 15, quad = lane >> 4;
  const int wr = wave >> 1, wc = wave & 1;

  for (int kt = 0; kt < D_MODEL / 64; ++kt) {
    const int k0 = kt * 64;
    stage_tile<128>(A + (size_t)m0 * D_MODEL + k0, D_MODEL, As, tid);
    stage_tile<128>(Bw + (size_t)e0 * D_MODEL + k0, D_MODEL, Bs, tid);
    __syncthreads();
#pragma unroll
    for (int ks = 0; ks < 2; ++ks) {
      bf16x8 af[4], bfr[4];
#pragma unroll
      for (int mi = 0; mi < 4; ++mi)
        af[mi] = *(const bf16x8*)(As + lds_off(wr * 64 + mi * 16 + l16, ks * 32 + quad * 8));
#pragma unroll
      for (int ci = 0; ci < 4; ++ci)
        bfr[ci] = *(const bf16x8*)(Bs + lds_off(wc * 64 + ci * 16 + l16, ks * 32 + quad * 8));
#pragma unroll
      for (int mi = 0; mi < 4; ++mi)
#pragma unroll
        for (int ci = 0; ci < 4; ++ci)
          acc[mi][ci] = __builtin_amdgcn_mfma_f32_16x16x32_bf16(af[mi], bfr[ci], acc[mi][ci], 0, 0, 0);
    }
    __syncthreads();
  }
}

// ---------------------------------------------------------------------------
// Fused Q/K/V projection. grid (32, 24): by -> {mat = by>>3, e0 = (by&7)*128}.
// mat 0 (q): LN epilogue with 0.125*log2e softmax/exp2 scale folded in.
// mat 1 (k): LN epilogue.
// mat 2 (v): V stored TRANSPOSED per (b,h), keys sigma-permuted within each
//            32-block so attn's in-register P^T fragment lines up with V.
// ---------------------------------------------------------------------------
__launch_bounds__(256)
__global__ void qkv_gemm(const unsigned short* __restrict__ xb,
                         const unsigned short* __restrict__ wb,   // wq|wk|wv bf16
                         const float* __restrict__ bq, const float* __restrict__ bk,
                         const float* __restrict__ bv,
                         const float* __restrict__ qg, const float* __restrict__ qbeta,
                         const float* __restrict__ kg, const float* __restrict__ kbeta,
                         unsigned short* __restrict__ qkout,      // qn | kn
                         unsigned short* __restrict__ vt) {
  __shared__ unsigned short As[128 * 64];
  __shared__ unsigned short Bs[128 * 64];
  const int m0  = blockIdx.x * 128;
  const int by  = blockIdx.y;
  const int mat = by >> 3;
  const int e0  = (by & 7) * 128;
  const unsigned short* Bw = wb + (size_t)mat * WEL;

  f32x4 acc[4][4];
#pragma unroll
  for (int mi = 0; mi < 4; ++mi)
#pragma unroll
    for (int ci = 0; ci < 4; ++ci) acc[mi][ci] = f32x4{0.f, 0.f, 0.f, 0.f};

  mainloop128(xb, Bw, m0, e0, As, Bs, acc);

  const int lane = threadIdx.x & 63, wave = threadIdx.x >> 6;
  const int l16 = lane & 15, quad = lane >> 4;
  const int wr = wave >> 1, wc = wave & 1;
  const int colbase = e0 + wc * 64;          // multiple of 64 -> one head per wave

  const float* bias = (mat == 0) ? bq : ((mat == 1) ? bk : bv);
  float bcol[4];
#pragma unroll
  for (int ci = 0; ci < 4; ++ci) bcol[ci] = bias[colbase + ci * 16 + l16];
#pragma unroll
  for (int mi = 0; mi < 4; ++mi)
#pragma unroll
    for (int ci = 0; ci < 4; ++ci)
#pragma unroll
      for (int r = 0; r < 4; ++r) acc[mi][ci][r] += bcol[ci];

  if (mat < 2) {
    const float* gamma = (mat == 0) ? qg : kg;
    const float* beta  = (mat == 0) ? qbeta : kbeta;
    // fold softmax scale AND log2(e) (attn uses exp2) into q
    const float sc = (mat == 0) ? 0.18033688011112042f : 1.0f;  // 0.125*log2e
    float g4[4], bt4[4];
#pragma unroll
    for (int ci = 0; ci < 4; ++ci) {
      g4[ci] = gamma[ci * 16 + l16] * sc;
      bt4[ci] = beta[ci * 16 + l16] * sc;
    }
#pragma unroll
    for (int mi = 0; mi < 4; ++mi)
#pragma unroll
      for (int r = 0; r < 4; ++r) {
        float s = acc[mi][0][r] + acc[mi][1][r] + acc[mi][2][r] + acc[mi][3][r];
        s += __shfl_xor(s, 1); s += __shfl_xor(s, 2);
        s += __shfl_xor(s, 4); s += __shfl_xor(s, 8);
        float mean = s * (1.f / 64.f);
        float d0 = acc[mi][0][r] - mean, d1 = acc[mi][1][r] - mean;
        float d2 = acc[mi][2][r] - mean, d3 = acc[mi][3][r] - mean;
        float q = d0 * d0 + d1 * d1 + d2 * d2 + d3 * d3;
        q += __shfl_xor(q, 1); q += __shfl_xor(q, 2);
        q += __shfl_xor(q, 4); q += __shfl_xor(q, 8);
        float rs = rsqrtf(q * (1.f / 64.f) + 1e-6f);
        acc[mi][0][r] = d0 * rs * g4[0] + bt4[0];
        acc[mi][1][r] = d1 * rs * g4[1] + bt4[1];
        acc[mi][2][r] = d2 * rs * g4[2] + bt4[2];
        acc[mi][3][r] = d3 * rs * g4[3] + bt4[3];
      }
    unsigned short* out = qkout + (size_t)mat * XEL;
#pragma unroll
    for (int mi = 0; mi < 4; ++mi)
#pragma unroll
      for (int ci = 0; ci < 4; ++ci) {
        int col = colbase + ci * 16 + l16;
#pragma unroll
        for (int r = 0; r < 4; ++r) {
          int row = m0 + wr * 64 + mi * 16 + quad * 4 + r;
          out[(size_t)row * D_MODEL + col] = f2bf(acc[mi][ci][r]);
        }
      }
  } else {
    // V transpose via wave-private LDS scratch (col-swizzled), then each lane
    // stores one full d-row (128B) as 8x dwordx4 -> coalesced.
    // Token index within 64 is sigma-permuted: logical t = 16*half+4*q+r
    // stored at phys = 8*q + 4*half + r (within its 32-block), matching the
    // attention kernel's in-register P^T bf16x8 fragment order.
    unsigned short* scr = ((wave < 2) ? As : Bs) + (size_t)(wave & 1) * 4096;
#pragma unroll
    for (int ci = 0; ci < 4; ++ci) {
      int dl = ci * 16 + l16;
      int sw = (dl & 3) * 16;
#pragma unroll
      for (int mi = 0; mi < 4; ++mi)
#pragma unroll
        for (int r = 0; r < 4; ++r) {
          // logical token t = mi*16 + quad*4 + r  (half = mi&1, block = mi>>1)
          int np = ((mi >> 1) << 5) + (quad << 3) + ((mi & 1) << 2) + r;
          scr[dl * 64 + (np ^ sw)] = f2bf(acc[mi][ci][r]);
        }
    }
    __builtin_amdgcn_wave_barrier();
    int row0 = m0 + wr * 64;                 // token base of this wave's tile
    int b = row0 >> 11, nb = row0 & 2047;
    int h = colbase >> 6;
    int dl = lane;                           // this lane's d within the head
    unsigned short* gdst = vt + ((size_t)((b * 16 + h) * 64 + dl) * N_SEQ + nb);
    const unsigned short* srow = scr + dl * 64;
    int sw = (dl & 3) * 16;
#pragma unroll
    for (int j = 0; j < 8; ++j) {
      uint4 vv = *(const uint4*)(srow + ((j * 8) ^ sw));
      *(uint4*)(gdst + j * 8) = vv;
    }
  }
}

// ---------------------------------------------------------------------------
// Output projection: fp32 out = ao * Wo^T + bo. grid (32, 8).
// ---------------------------------------------------------------------------
__launch_bounds__(256)
__global__ void out_gemm(const unsigned short* __restrict__ ao,
                         const unsigned short* __restrict__ wob,
                         const float* __restrict__ bo,
                         float* __restrict__ out) {
  __shared__ unsigned short As[128 * 64];
  __shared__ unsigned short Bs[128 * 64];
  const int m0 = blockIdx.x * 128;
  const int e0 = blockIdx.y * 128;

  f32x4 acc[4][4];
#pragma unroll
  for (int mi = 0; mi < 4; ++mi)
#pragma unroll
    for (int ci = 0; ci < 4; ++ci) acc[mi][ci] = f32x4{0.f, 0.f, 0.f, 0.f};

  mainloop128(ao, wob, m0, e0, As, Bs, acc);

  const int lane = threadIdx.x & 63, wave = threadIdx.x >> 6;
  const int l16 = lane & 15, quad = lane >> 4;
  const int wr = wave >> 1, wc = wave & 1;
  float bcol[4];
#pragma unroll
  for (int ci = 0; ci < 4; ++ci) bcol[ci] = bo[e0 + wc * 64 + ci * 16 + l16];
#pragma unroll
  for (int mi = 0; mi < 4; ++mi)
#pragma unroll
    for (int ci = 0; ci < 4; ++ci) {
      int col = e0 + wc * 64 + ci * 16 + l16;
#pragma unroll
      for (int r = 0; r < 4; ++r) {
        int row = m0 + wr * 64 + mi * 16 + quad * 4 + r;
        out[(size_t)row * D_MODEL + col] = acc[mi][ci][r] + bcol[ci];
      }
    }
}

// ---------------------------------------------------------------------------
// Flash attention, swapped-operand QK^T, 8 waves / 512 threads per block.
// Wave pair (2p, 2p+1): wave 2p keys [0,32), wave 2p+1 keys [32,64) of the
// shared q-rows [p*32, p*32+32).
// R5: depth-3 circular K/V buffers + counted vmcnt (R4) at 48KB LDS — Q's
// 16KB now OVERLAYS K-bufs 0/1 (aq is register-resident after the prologue),
// restoring 2 blocks/CU (R4's 64KB dropped residency to 1 block: usable
// concurrent LDS/CU measured in [96,128)KB, not 160KB).
// Layout: K bufs smem + i*4096 (i=0..2), V bufs smem + 12288 + i*4096.
// vmcnt(6) = this iter's bias(4)+stage(2); never drained in the main loop.
// ---------------------------------------------------------------------------
__launch_bounds__(512)
__global__ void attn_kernel(const unsigned short* __restrict__ Q,
                            const unsigned short* __restrict__ Kn,
                            const unsigned short* __restrict__ Vt,
                            const float* __restrict__ bias,
                            unsigned short* __restrict__ Out) {
  __shared__ unsigned short smem[24576];     // 48KB

  const int tid  = threadIdx.x;
  const int wave = tid >> 6, lane = tid & 63;
  const int quad = lane >> 4, l16 = lane & 15;
  const int pairId = wave >> 1;              // 4 pairs x 32 q-rows
  const int kh = wave & 1;                   // key half of the 64-key tile
  const int bidx = blockIdx.x;
  const int qt = bidx & 15;                  // 16 q-tiles of 128
  const int h  = (bidx >> 4) & 15;
  const int b  = bidx >> 8;
  const int q0 = qt * 128;
  const size_t base  = (size_t)b * N_SEQ * D_MODEL + (size_t)h * 64;
  const unsigned short* vtb = Vt + (size_t)(b * 16 + h) * 64 * N_SEQ;

  // bias row pointers for this lane's q-rows (S^T layout: q = l16)
  const float* brow[2];
#pragma unroll
  for (int mi = 0; mi < 2; ++mi)
    brow[mi] = bias + ((size_t)b * N_SEQ + q0 + pairId * 32 + mi * 16 + l16) * N_SEQ;
  const int bcol0 = kh * 32 + quad * 4;      // this wave's key columns

  // ---- prologue phase 1: Q through LDS (overlays K-bufs 0/1), to regs ----
  stage_tile<128, 512>(Q + base + (size_t)q0 * D_MODEL, D_MODEL, smem, tid);
  __syncthreads();                           // Q DMA landed (vmcnt0) + barrier

  bf16x8 aq[2][2];                           // [mi][ks] — shared by the pair
#pragma unroll
  for (int mi = 0; mi < 2; ++mi)
#pragma unroll
    for (int ks = 0; ks < 2; ++ks)
      aq[mi][ks] = *(const bf16x8*)(smem + lds_off(pairId * 32 + mi * 16 + l16, ks * 32 + quad * 8));
  __syncthreads();                           // all waves read Q; safe to reuse

  // ---- prologue phase 2: bias tile 0 + stage K/V tiles 0,1 ----
  f32x4 bcur[2][2], bnxt[2][2];
#pragma unroll
  for (int mi = 0; mi < 2; ++mi)
#pragma unroll
    for (int cl = 0; cl < 2; ++cl)
      bcur[mi][cl] = *(const f32x4*)(brow[mi] + bcol0 + cl * 16);

  stage_tile<64, 512>(Kn + base, D_MODEL, smem, tid);
  stage_tile<64, 512>(vtb, N_SEQ, smem + 12288, tid);
  stage_tile<64, 512>(Kn + base + (size_t)64 * D_MODEL, D_MODEL, smem + 4096, tid);
  stage_tile<64, 512>(vtb + 64, N_SEQ, smem + 12288 + 4096, tid);

  WAITV(2);                                  // bias+tile0 done; tile1 in flight
  __builtin_amdgcn_s_barrier();
  __builtin_amdgcn_sched_barrier(0);

  f32x4 o[2][4];                             // O^T partial: d = cd*16+quad*4+r, q = l16
#pragma unroll
  for (int mi = 0; mi < 2; ++mi)
#pragma unroll
    for (int cd = 0; cd < 4; ++cd) o[mi][cd] = f32x4{0.f, 0.f, 0.f, 0.f};
  float lsum[2] = {0.f, 0.f};
  constexpr float LOG2E = 1.44269504088896340736f;

  constexpr int NT = N_SEQ / 64;
  for (int kt = 0; kt < NT; ++kt) {
    const int cur = kt % 3;
    unsigned short* Kcur = smem + cur * 4096;
    unsigned short* Vcur = smem + 12288 + cur * 4096;

    // bias for kt+1 FIRST (issue order matters for in-order vmcnt retirement)
    if (kt + 1 < NT) {
#pragma unroll
      for (int mi = 0; mi < 2; ++mi)
#pragma unroll
        for (int cl = 0; cl < 2; ++cl)
          bnxt[mi][cl] = *(const f32x4*)(brow[mi] + (kt + 1) * 64 + bcol0 + cl * 16);
    }
    // stage tile kt+2 into buf (kt+2)%3 (read last at iteration kt-1;
    // the barrier at end of kt-1 made it safe to overwrite)
    if (kt + 2 < NT) {
      const int nb = (kt + 2) % 3;
      stage_tile<64, 512>(Kn + base + (size_t)(kt + 2) * 64 * D_MODEL, D_MODEL,
                          smem + nb * 4096, tid);
      stage_tile<64, 512>(vtb + (kt + 2) * 64, N_SEQ,
                          smem + 12288 + nb * 4096, tid);
    }

    // S^T = K Q^T for this wave's 32 keys (q pre-scaled by 0.125*log2e)
    f32x4 sfT[2][2];                         // [mi][cl]: key = kh*32+cl*16+quad*4+r, q = l16
#pragma unroll
    for (int cl = 0; cl < 2; ++cl) {
      const int c = kh * 2 + cl;
      bf16x8 k0 = *(const bf16x8*)(Kcur + lds_off(c * 16 + l16, quad * 8));
      bf16x8 k1 = *(const bf16x8*)(Kcur + lds_off(c * 16 + l16, 32 + quad * 8));
#pragma unroll
      for (int mi = 0; mi < 2; ++mi) {
        f32x4 z = f32x4{0.f, 0.f, 0.f, 0.f};
        z = __builtin_amdgcn_mfma_f32_16x16x32_bf16(k0, aq[mi][0], z, 0, 0, 0);
        sfT[mi][cl] = __builtin_amdgcn_mfma_f32_16x16x32_bf16(k1, aq[mi][1], z, 0, 0, 0);
      }
    }

    // p = 2^(sT + bias*log2e); accumulate partial l; pack P^T to one bf16 frag
    // per mi (this wave's 32 keys), k-slot order matches sigma-permuted Vt.
    union PafU { unsigned int w[4]; bf16x8 v; };
    PafU paf[2];
#pragma unroll
    for (int mi = 0; mi < 2; ++mi)
#pragma unroll
      for (int cl = 0; cl < 2; ++cl) {
        float p0 = exp2fast(fmaf(bcur[mi][cl][0], LOG2E, sfT[mi][cl][0]));
        float p1 = exp2fast(fmaf(bcur[mi][cl][1], LOG2E, sfT[mi][cl][1]));
        float p2 = exp2fast(fmaf(bcur[mi][cl][2], LOG2E, sfT[mi][cl][2]));
        float p3 = exp2fast(fmaf(bcur[mi][cl][3], LOG2E, sfT[mi][cl][3]));
        lsum[mi] += (p0 + p1) + (p2 + p3);
        paf[mi].w[cl * 2]     = cvt_pk_bf16(p0, p1);
        paf[mi].w[cl * 2 + 1] = cvt_pk_bf16(p2, p3);
      }

    // O^T += V^T P^T over this wave's 32 keys (V frags reused across both mi)
    {
      bf16x8 bv[4];
#pragma unroll
      for (int cd = 0; cd < 4; ++cd)
        bv[cd] = *(const bf16x8*)(Vcur + lds_off(cd * 16 + l16, kh * 32 + quad * 8));
#pragma unroll
      for (int mi = 0; mi < 2; ++mi)
#pragma unroll
        for (int cd = 0; cd < 4; ++cd)
          o[mi][cd] = __builtin_amdgcn_mfma_f32_16x16x32_bf16(bv[cd], paf[mi].v, o[mi][cd], 0, 0, 0);
    }

#pragma unroll
    for (int mi = 0; mi < 2; ++mi)
#pragma unroll
      for (int cl = 0; cl < 2; ++cl) bcur[mi][cl] = bnxt[mi][cl];

    // counted wait: guarantee tile kt+1 (staged at kt-1) landed, leave this
    // iteration's bias(4)+stage(2) in flight; raw barrier (no vmcnt(0) drain)
    if (kt + 1 < NT) {
      if (kt < NT - 2) { WAITV(6); } else { WAITV(4); }
      __builtin_amdgcn_s_barrier();
      __builtin_amdgcn_sched_barrier(0);
    }
  }

  // drain any stragglers before reusing K-buffer LDS as reduction scratch
  WAITV(0);
  __syncthreads();

  // ---- pair reduction: odd wave dumps partial O + lsum to (dead) LDS ----
  float* red = (float*)smem;                 // need 8704 floats = 34816B < 48KB
  float* slot = red + (size_t)(pairId * 64 + lane) * 34;
  if (kh) {
#pragma unroll
    for (int mi = 0; mi < 2; ++mi)
#pragma unroll
      for (int cd = 0; cd < 4; ++cd)
#pragma unroll
        for (int r = 0; r < 4; ++r)
          slot[mi * 16 + cd * 4 + r] = o[mi][cd][r];
    slot[32] = lsum[0];
    slot[33] = lsum[1];
  }
  __syncthreads();
  if (!kh) {
#pragma unroll
    for (int mi = 0; mi < 2; ++mi)
#pragma unroll
      for (int cd = 0; cd < 4; ++cd)
#pragma unroll
        for (int r = 0; r < 4; ++r)
          o[mi][cd][r] += slot[mi * 16 + cd * 4 + r];
    lsum[0] += slot[32];
    lsum[1] += slot[33];

    // normalize: lsum and O^T columns are both indexed by q = l16 -> lane-local
#pragma unroll
    for (int mi = 0; mi < 2; ++mi) {
      float l = lsum[mi];
      l += __shfl_xor(l, 16);
      l += __shfl_xor(l, 32);
      float inv = 1.0f / l;
      size_t row = (size_t)b * N_SEQ + q0 + pairId * 32 + mi * 16 + l16;
#pragma unroll
      for (int cd = 0; cd < 4; ++cd) {
        uint2 vv;
        vv.x = cvt_pk_bf16(o[mi][cd][0] * inv, o[mi][cd][1] * inv);
        vv.y = cvt_pk_bf16(o[mi][cd][2] * inv, o[mi][cd][3] * inv);
        *(uint2*)(Out + row * D_MODEL + h * 64 + cd * 16 + quad * 4) = vv;
      }
    }
  }
}

extern "C" void kernel_launch(void* const* d_in, const int* in_sizes, int n_in,
                              void* d_out, int out_size, void* d_ws, size_t ws_size,
                              hipStream_t stream) {
  const float* x    = (const float*)d_in[0];
  const float* bias = (const float*)d_in[1];
  const float* Wq = (const float*)d_in[2];  const float* bq = (const float*)d_in[3];
  const float* Wk = (const float*)d_in[4];  const float* bk = (const float*)d_in[5];
  const float* Wv = (const float*)d_in[6];  const float* bv = (const float*)d_in[7];
  const float* Wo = (const float*)d_in[8];  const float* bo = (const float*)d_in[9];
  const float* qg = (const float*)d_in[10]; const float* qb = (const float*)d_in[11];
  const float* kg = (const float*)d_in[12]; const float* kb = (const float*)d_in[13];
  float* out = (float*)d_out;

  unsigned short* wsb = (unsigned short*)d_ws;
  unsigned short* xb  = wsb;                 // 4M (reused as ao after qkv_gemm)
  unsigned short* wqb = wsb + XEL;           // 4 x 1M weights
  unsigned short* wob = wsb + XEL + 3 * WEL;
  unsigned short* qn  = wsb + XEL + 4 * WEL; // 4M
  unsigned short* kn  = qn + XEL;            // 4M
  unsigned short* vt  = qn + 2 * XEL;        // 4M, transposed + key-permuted
  unsigned short* ao  = xb;                  // alias: xb dead after qkv_gemm

  dim3 blk(256, 1, 1);

  cvt_kernel<<<dim3((unsigned)((XEL + 4 * WEL) / (256 * 8)), 1, 1), blk, 0, stream>>>(
      x, Wq, Wk, Wv, Wo, wsb);

  qkv_gemm<<<dim3(M_ROWS / 128, 24, 1), blk, 0, stream>>>(
      xb, wqb, bq, bk, bv, qg, qb, kg, kb, qn, vt);

  attn_kernel<<<dim3(N_B * 16 * (N_SEQ / 128), 1, 1), dim3(512, 1, 1), 0, stream>>>(
      qn, kn, vt, bias, ao);

  out_gemm<<<dim3(M_ROWS / 128, D_MODEL / 128, 1), blk, 0, stream>>>(ao, wob, bo, out);
}